// Round 9
// baseline (371.330 us; speedup 1.0000x reference)
//
#include <hip/hip_runtime.h>
#include <math.h>

#define N_NODES_C 100000
#define N_EDGES_C 3200000
#define NB 782        // ceil(100000 / 128) buckets of 128 nodes
#define BNODES 128
#define LDS_CAP 6144  // per-bucket LDS staging capacity (mean ~4092, +32 sigma)
#define CHUNK 16384   // edges per partition block
#define NBLK 196      // ceil(N_EDGES_C / CHUNK)

typedef unsigned short u16;

__device__ __forceinline__ float bf2f(u16 u) {
    unsigned int t = ((unsigned int)u) << 16;
    return __uint_as_float(t);
}
__device__ __forceinline__ u16 f2bf(float f) {  // round-to-nearest-even
    unsigned int x = __float_as_uint(f);
    x += 0x7fffu + ((x >> 16) & 1u);
    return (u16)(x >> 16);
}

// ============================ atomic-free bucketed partition ============================

__global__ __launch_bounds__(256) void passA_hist_kernel(const int* __restrict__ dst,
                                                         int* __restrict__ cnt, int n_edges) {
    __shared__ int h[NB];
    for (int i = threadIdx.x; i < NB; i += 256) h[i] = 0;
    __syncthreads();
    const int blk = blockIdx.x;
    const int end = min((blk + 1) * CHUNK, n_edges);
    for (int e = blk * CHUNK + threadIdx.x; e < end; e += 256)
        atomicAdd(&h[dst[e] >> 7], 1);
    __syncthreads();
    for (int i = threadIdx.x; i < NB; i += 256) cnt[i * NBLK + blk] = h[i];
}

__global__ __launch_bounds__(256) void scan_chunks_kernel(int* __restrict__ a, int n, int* __restrict__ bsums) {
    __shared__ int s[256];
    const int tid = threadIdx.x;
    int base = blockIdx.x * 1024 + tid * 4;
    int v[4];
#pragma unroll
    for (int i = 0; i < 4; ++i) v[i] = (base + i < n) ? a[base + i] : 0;
    int tsum = v[0] + v[1] + v[2] + v[3];
    s[tid] = tsum;
    __syncthreads();
    for (int off = 1; off < 256; off <<= 1) {
        int t = (tid >= off) ? s[tid - off] : 0;
        __syncthreads();
        s[tid] += t;
        __syncthreads();
    }
    int run = s[tid] - tsum;
#pragma unroll
    for (int i = 0; i < 4; ++i) {
        run += v[i];
        if (base + i < n) a[base + i] = run;
    }
    if (tid == 255) bsums[blockIdx.x] = s[255];
}

__global__ __launch_bounds__(256) void scan_sums_kernel(int* __restrict__ bsums, int nb) {
    __shared__ int s[256];
    const int tid = threadIdx.x;
    int v = (tid < nb) ? bsums[tid] : 0;
    s[tid] = v;
    __syncthreads();
    for (int off = 1; off < 256; off <<= 1) {
        int t = (tid >= off) ? s[tid - off] : 0;
        __syncthreads();
        s[tid] += t;
        __syncthreads();
    }
    if (tid < nb) bsums[tid] = s[tid] - v;
}

__global__ __launch_bounds__(256) void scan_add_kernel(int* __restrict__ a, int n, const int* __restrict__ bsums) {
    int base = blockIdx.x * 1024 + threadIdx.x * 4;
    int add = bsums[blockIdx.x];
#pragma unroll
    for (int i = 0; i < 4; ++i)
        if (base + i < n) a[base + i] += add;
}

__global__ __launch_bounds__(1024) void boffs_kernel(const int* __restrict__ incl,
                                                     int* __restrict__ boffs,
                                                     int* __restrict__ offs) {
    const int b = threadIdx.x;
    if (b < NB) boffs[b] = b ? incl[b * NBLK - 1] : 0;
    if (b == 0) {
        int total = incl[NB * NBLK - 1];
        boffs[NB] = total;
        offs[N_NODES_C] = total;
    }
}

// pass B (LDS sort): block-local counting sort by bucket, then burst-write each run
__global__ __launch_bounds__(256) void passB_sort_kernel(const int* __restrict__ src,
                                                         const int* __restrict__ dst,
                                                         const int* __restrict__ incl,
                                                         unsigned int* __restrict__ stage,
                                                         int n_edges) {
    __shared__ unsigned int sdst[CHUNK];    // 64 KB
    __shared__ unsigned int spack[CHUNK];   // 64 KB
    __shared__ int hist[NB];
    __shared__ int lcur[NB];
    __shared__ int tsum[256];
    const int blk = blockIdx.x, tid = threadIdx.x;
    const int e0 = blk * CHUNK;
    const int cntE = min(CHUNK, n_edges - e0);

    for (int b = tid; b < NB; b += 256) hist[b] = 0;
    __syncthreads();

    if (cntE == CHUNK) {
        for (int i = tid * 4; i < CHUNK; i += 1024) {
            int4 d4 = *(const int4*)&dst[e0 + i];
            sdst[i + 0] = (unsigned)d4.x; sdst[i + 1] = (unsigned)d4.y;
            sdst[i + 2] = (unsigned)d4.z; sdst[i + 3] = (unsigned)d4.w;
            atomicAdd(&hist[d4.x >> 7], 1); atomicAdd(&hist[d4.y >> 7], 1);
            atomicAdd(&hist[d4.z >> 7], 1); atomicAdd(&hist[d4.w >> 7], 1);
        }
    } else {
        for (int i = tid; i < cntE; i += 256) {
            int d = dst[e0 + i];
            sdst[i] = (unsigned)d;
            atomicAdd(&hist[d >> 7], 1);
        }
    }
    __syncthreads();

    {
        int loc[4];
        const int bi = tid * 4;
        int s = 0;
#pragma unroll
        for (int k = 0; k < 4; ++k) {
            int idx = bi + k;
            loc[k] = (idx < NB) ? hist[idx] : 0;
            s += loc[k];
        }
        tsum[tid] = s;
        __syncthreads();
        for (int off = 1; off < 256; off <<= 1) {
            int t = (tid >= off) ? tsum[tid - off] : 0;
            __syncthreads();
            tsum[tid] += t;
            __syncthreads();
        }
        int run = tsum[tid] - s;
#pragma unroll
        for (int k = 0; k < 4; ++k) {
            int idx = bi + k;
            if (idx < NB) {
                int h = loc[k];
                hist[idx] = run;
                lcur[idx] = run;
                run += h;
            }
        }
    }
    __syncthreads();

    if (cntE == CHUNK) {
        for (int i = tid * 4; i < CHUNK; i += 1024) {
            int4 s4 = *(const int4*)&src[e0 + i];
            unsigned int d; int p;
            d = sdst[i + 0]; p = atomicAdd(&lcur[d >> 7], 1); spack[p] = (unsigned)s4.x | ((d & 127u) << 17);
            d = sdst[i + 1]; p = atomicAdd(&lcur[d >> 7], 1); spack[p] = (unsigned)s4.y | ((d & 127u) << 17);
            d = sdst[i + 2]; p = atomicAdd(&lcur[d >> 7], 1); spack[p] = (unsigned)s4.z | ((d & 127u) << 17);
            d = sdst[i + 3]; p = atomicAdd(&lcur[d >> 7], 1); spack[p] = (unsigned)s4.w | ((d & 127u) << 17);
        }
    } else {
        for (int i = tid; i < cntE; i += 256) {
            unsigned int d = sdst[i];
            int p = atomicAdd(&lcur[d >> 7], 1);
            spack[p] = (unsigned)src[e0 + i] | ((d & 127u) << 17);
        }
    }
    __syncthreads();

    for (int b = tid; b < NB; b += 256) {
        int l0 = hist[b];
        int l1 = (b + 1 < NB) ? hist[b + 1] : cntE;
        int idx = b * NBLK + blk;
        int g0 = idx ? incl[idx - 1] : 0;
        for (int j = l0; j < l1; ++j) stage[g0 + (j - l0)] = spack[j];
    }
}

__global__ __launch_bounds__(256) void bucket_finalize_kernel(const unsigned int* __restrict__ stage,
                                                              const int* __restrict__ boffs,
                                                              int* __restrict__ offs,
                                                              int* __restrict__ srcs) {
    __shared__ int hist[BNODES];
    __shared__ int excl[BNODES];
    __shared__ int curs[BNODES];
    __shared__ int sbuf[LDS_CAP];
    const int b = blockIdx.x, tid = threadIdx.x;
    const int base = boffs[b];
    const int count = boffs[b + 1] - base;
    const int n0 = b * BNODES;
    for (int i = tid; i < BNODES; i += 256) hist[i] = 0;
    __syncthreads();
    for (int i = tid; i < count; i += 256) {
        unsigned int w = stage[base + i];
        atomicAdd(&hist[w >> 17], 1);
    }
    __syncthreads();
    if (tid < BNODES) excl[tid] = hist[tid];
    __syncthreads();
    for (int off = 1; off < BNODES; off <<= 1) {
        int t = 0;
        if (tid < BNODES && tid >= off) t = excl[tid - off];
        __syncthreads();
        if (tid < BNODES) excl[tid] += t;
        __syncthreads();
    }
    if (tid < BNODES) {
        int ex = excl[tid] - hist[tid];
        int n = n0 + tid;
        if (n < N_NODES_C) offs[n] = base + ex;
        curs[tid] = ex;
    }
    __syncthreads();
    if (count <= LDS_CAP) {
        for (int i = tid; i < count; i += 256) {
            unsigned int w = stage[base + i];
            int p = atomicAdd(&curs[w >> 17], 1);
            sbuf[p] = (int)(w & 0x1FFFFu);
        }
        __syncthreads();
        for (int i = tid; i < count; i += 256) srcs[base + i] = sbuf[i];
    } else {
        for (int i = tid; i < count; i += 256) {
            unsigned int w = stage[base + i];
            int p = atomicAdd(&curs[w >> 17], 1);
            srcs[base + p] = (int)(w & 0x1FFFFu);
        }
    }
}

// ====== gather64v (bf16 feats): 16 lanes/row, 4 row-slots/wave, 16-row unroll ======

__global__ __launch_bounds__(256) void gather64v_kernel(const u16* __restrict__ feat,
                                                        const int* __restrict__ offs,
                                                        const int* __restrict__ srcs,
                                                        const float* __restrict__ bias,
                                                        float* __restrict__ out, int n_nodes) {
    const int wave = threadIdx.x >> 6;
    const int lane = threadIdx.x & 63;
    const int grp  = lane >> 4;
    const int cl   = lane & 15;
    const int n = blockIdx.x * 4 + wave;
    if (n >= n_nodes) return;

    float a0 = 0.f, a1 = 0.f, a2 = 0.f, a3 = 0.f;
    if (grp == 0) {
        ushort4 v = *(const ushort4*)&feat[(size_t)n * 64 + cl * 4];
        a0 = bf2f(v.x); a1 = bf2f(v.y); a2 = bf2f(v.z); a3 = bf2f(v.w);
    }
    const int s0 = offs[n], s1 = offs[n + 1];
    int i = s0;
    for (; i + 16 <= s1; i += 16) {
        int r0 = srcs[i + grp];
        int r1 = srcs[i + 4 + grp];
        int r2 = srcs[i + 8 + grp];
        int r3 = srcs[i + 12 + grp];
        ushort4 v0 = *(const ushort4*)&feat[(size_t)r0 * 64 + cl * 4];
        ushort4 v1 = *(const ushort4*)&feat[(size_t)r1 * 64 + cl * 4];
        ushort4 v2 = *(const ushort4*)&feat[(size_t)r2 * 64 + cl * 4];
        ushort4 v3 = *(const ushort4*)&feat[(size_t)r3 * 64 + cl * 4];
        a0 += bf2f(v0.x); a1 += bf2f(v0.y); a2 += bf2f(v0.z); a3 += bf2f(v0.w);
        a0 += bf2f(v1.x); a1 += bf2f(v1.y); a2 += bf2f(v1.z); a3 += bf2f(v1.w);
        a0 += bf2f(v2.x); a1 += bf2f(v2.y); a2 += bf2f(v2.z); a3 += bf2f(v2.w);
        a0 += bf2f(v3.x); a1 += bf2f(v3.y); a2 += bf2f(v3.z); a3 += bf2f(v3.w);
    }
    for (; i + 4 <= s1; i += 4) {
        int r = srcs[i + grp];
        ushort4 v = *(const ushort4*)&feat[(size_t)r * 64 + cl * 4];
        a0 += bf2f(v.x); a1 += bf2f(v.y); a2 += bf2f(v.z); a3 += bf2f(v.w);
    }
    if (i + grp < s1) {
        int r = srcs[i + grp];
        ushort4 v = *(const ushort4*)&feat[(size_t)r * 64 + cl * 4];
        a0 += bf2f(v.x); a1 += bf2f(v.y); a2 += bf2f(v.z); a3 += bf2f(v.w);
    }
    a0 += __shfl_xor(a0, 16); a1 += __shfl_xor(a1, 16);
    a2 += __shfl_xor(a2, 16); a3 += __shfl_xor(a3, 16);
    a0 += __shfl_xor(a0, 32); a1 += __shfl_xor(a1, 32);
    a2 += __shfl_xor(a2, 32); a3 += __shfl_xor(a3, 32);
    if (lane < 16) {
        float4 b = *(const float4*)&bias[cl * 4];
        float4 o;
        o.x = fmaxf(a0 + b.x, 0.f);
        o.y = fmaxf(a1 + b.y, 0.f);
        o.z = fmaxf(a2 + b.z, 0.f);
        o.w = fmaxf(a3 + b.w, 0.f);
        *(float4*)&out[(size_t)n * 64 + cl * 4] = o;
    }
}

// GEMM quad-step macro: acc[4][4] += a{0..3}.{x,y,z,w} * w{0..3}
#define GIN_STEP(ai, i)                                                                               \
    acc[i][0] += ai.x * w0.x; acc[i][1] += ai.x * w0.y; acc[i][2] += ai.x * w0.z; acc[i][3] += ai.x * w0.w; \
    acc[i][0] += ai.y * w1.x; acc[i][1] += ai.y * w1.y; acc[i][2] += ai.y * w1.z; acc[i][3] += ai.y * w1.w; \
    acc[i][0] += ai.z * w2.x; acc[i][1] += ai.z * w2.y; acc[i][2] += ai.z * w2.z; acc[i][3] += ai.z * w2.w; \
    acc[i][0] += ai.w * w3.x; acc[i][1] += ai.w * w3.y; acc[i][2] += ai.w * w3.z; acc[i][3] += ai.w * w3.w;

// ====== dense128: out_bf16 = x @ W1  (no LDS, no barriers; W via L1, rows broadcast) ======

__global__ __launch_bounds__(256) void dense128_kernel(const float* __restrict__ in,
                                                       const float* __restrict__ W,
                                                       u16* __restrict__ out, int n_nodes) {
    const int tid = threadIdx.x;
    const int tj = tid & 15, tn = tid >> 4;
    const int j0 = tj * 4, n0 = blockIdx.x * 64 + tn * 4;
    const int r0 = min(n0 + 0, n_nodes - 1), r1 = min(n0 + 1, n_nodes - 1);
    const int r2 = min(n0 + 2, n_nodes - 1), r3 = min(n0 + 3, n_nodes - 1);
    float acc[4][4];
#pragma unroll
    for (int i = 0; i < 4; ++i)
#pragma unroll
        for (int j = 0; j < 4; ++j) acc[i][j] = 0.f;
    for (int k = 0; k < 128; k += 4) {
        float4 a0 = *(const float4*)&in[(size_t)r0 * 128 + k];
        float4 a1 = *(const float4*)&in[(size_t)r1 * 128 + k];
        float4 a2 = *(const float4*)&in[(size_t)r2 * 128 + k];
        float4 a3 = *(const float4*)&in[(size_t)r3 * 128 + k];
        float4 w0 = *(const float4*)&W[(k + 0) * 64 + j0];
        float4 w1 = *(const float4*)&W[(k + 1) * 64 + j0];
        float4 w2 = *(const float4*)&W[(k + 2) * 64 + j0];
        float4 w3 = *(const float4*)&W[(k + 3) * 64 + j0];
        GIN_STEP(a0, 0) GIN_STEP(a1, 1) GIN_STEP(a2, 2) GIN_STEP(a3, 3)
    }
#pragma unroll
    for (int i = 0; i < 4; ++i) {
        int n = n0 + i;
        if (n < n_nodes) {
            ushort4 o;
            o.x = f2bf(acc[i][0]); o.y = f2bf(acc[i][1]);
            o.z = f2bf(acc[i][2]); o.w = f2bf(acc[i][3]);
            *(ushort4*)&out[(size_t)n * 64 + j0] = o;
        }
    }
}

// ====== fused: T = relu(in@W2 + b2); out_bf16 = T @ W3  (only T in LDS, 1 barrier) ======

__global__ __launch_bounds__(256) void fused_w2w3_kernel(const float* __restrict__ in,
                                                         const float* __restrict__ W2,
                                                         const float* __restrict__ b2,
                                                         const float* __restrict__ W3,
                                                         u16* __restrict__ out, int n_nodes) {
    __shared__ float sT[64][68];
    const int tid = threadIdx.x;
    const int tj = tid & 15, tn = tid >> 4;
    const int j0 = tj * 4, n0l = tn * 4;
    const int base = blockIdx.x * 64;
    const int r0 = min(base + n0l + 0, n_nodes - 1), r1 = min(base + n0l + 1, n_nodes - 1);
    const int r2 = min(base + n0l + 2, n_nodes - 1), r3 = min(base + n0l + 3, n_nodes - 1);
    float acc[4][4];
#pragma unroll
    for (int i = 0; i < 4; ++i)
#pragma unroll
        for (int j = 0; j < 4; ++j) acc[i][j] = b2[j0 + j];
    for (int k = 0; k < 64; k += 4) {
        float4 a0 = *(const float4*)&in[(size_t)r0 * 64 + k];
        float4 a1 = *(const float4*)&in[(size_t)r1 * 64 + k];
        float4 a2 = *(const float4*)&in[(size_t)r2 * 64 + k];
        float4 a3 = *(const float4*)&in[(size_t)r3 * 64 + k];
        float4 w0 = *(const float4*)&W2[(k + 0) * 64 + j0];
        float4 w1 = *(const float4*)&W2[(k + 1) * 64 + j0];
        float4 w2 = *(const float4*)&W2[(k + 2) * 64 + j0];
        float4 w3 = *(const float4*)&W2[(k + 3) * 64 + j0];
        GIN_STEP(a0, 0) GIN_STEP(a1, 1) GIN_STEP(a2, 2) GIN_STEP(a3, 3)
    }
#pragma unroll
    for (int i = 0; i < 4; ++i) {
        float4 t;
        t.x = fmaxf(acc[i][0], 0.f); t.y = fmaxf(acc[i][1], 0.f);
        t.z = fmaxf(acc[i][2], 0.f); t.w = fmaxf(acc[i][3], 0.f);
        *(float4*)&sT[n0l + i][j0] = t;
    }
    __syncthreads();
#pragma unroll
    for (int i = 0; i < 4; ++i)
#pragma unroll
        for (int j = 0; j < 4; ++j) acc[i][j] = 0.f;
    for (int k = 0; k < 64; k += 4) {
        float4 a0 = *(const float4*)&sT[n0l + 0][k];
        float4 a1 = *(const float4*)&sT[n0l + 1][k];
        float4 a2 = *(const float4*)&sT[n0l + 2][k];
        float4 a3 = *(const float4*)&sT[n0l + 3][k];
        float4 w0 = *(const float4*)&W3[(k + 0) * 64 + j0];
        float4 w1 = *(const float4*)&W3[(k + 1) * 64 + j0];
        float4 w2 = *(const float4*)&W3[(k + 2) * 64 + j0];
        float4 w3 = *(const float4*)&W3[(k + 3) * 64 + j0];
        GIN_STEP(a0, 0) GIN_STEP(a1, 1) GIN_STEP(a2, 2) GIN_STEP(a3, 3)
    }
#pragma unroll
    for (int i = 0; i < 4; ++i) {
        int n = base + n0l + i;
        if (n < n_nodes) {
            ushort4 o;
            o.x = f2bf(acc[i][0]); o.y = f2bf(acc[i][1]);
            o.z = f2bf(acc[i][2]); o.w = f2bf(acc[i][3]);
            *(ushort4*)&out[(size_t)n * 64 + j0] = o;
        }
    }
}

// ====== fused final: T = relu(in@W4+b4); logits = T@Wf+bf; out = log_softmax  (sT+sLog in LDS) ======

__global__ __launch_bounds__(256) void fused_w4final_kernel(const float* __restrict__ in,
                                                            const float* __restrict__ W4,
                                                            const float* __restrict__ b4,
                                                            const float* __restrict__ Wf,
                                                            const float* __restrict__ bfin,
                                                            float* __restrict__ out, int n_nodes) {
    __shared__ float sT[64][68];
    __shared__ float sLog[64][40];
    const int tid = threadIdx.x;
    const int base = blockIdx.x * 64;
    {
        const int tj = tid & 15, tn = tid >> 4;
        const int j0 = tj * 4, n0l = tn * 4;
        const int r0 = min(base + n0l + 0, n_nodes - 1), r1 = min(base + n0l + 1, n_nodes - 1);
        const int r2 = min(base + n0l + 2, n_nodes - 1), r3 = min(base + n0l + 3, n_nodes - 1);
        float acc[4][4];
#pragma unroll
        for (int i = 0; i < 4; ++i)
#pragma unroll
            for (int j = 0; j < 4; ++j) acc[i][j] = b4[j0 + j];
        for (int k = 0; k < 64; k += 4) {
            float4 a0 = *(const float4*)&in[(size_t)r0 * 64 + k];
            float4 a1 = *(const float4*)&in[(size_t)r1 * 64 + k];
            float4 a2 = *(const float4*)&in[(size_t)r2 * 64 + k];
            float4 a3 = *(const float4*)&in[(size_t)r3 * 64 + k];
            float4 w0 = *(const float4*)&W4[(k + 0) * 64 + j0];
            float4 w1 = *(const float4*)&W4[(k + 1) * 64 + j0];
            float4 w2 = *(const float4*)&W4[(k + 2) * 64 + j0];
            float4 w3 = *(const float4*)&W4[(k + 3) * 64 + j0];
            GIN_STEP(a0, 0) GIN_STEP(a1, 1) GIN_STEP(a2, 2) GIN_STEP(a3, 3)
        }
#pragma unroll
        for (int i = 0; i < 4; ++i) {
            float4 t;
            t.x = fmaxf(acc[i][0], 0.f); t.y = fmaxf(acc[i][1], 0.f);
            t.z = fmaxf(acc[i][2], 0.f); t.w = fmaxf(acc[i][3], 0.f);
            *(float4*)&sT[n0l + i][j0] = t;
        }
    }
    __syncthreads();
    if (tid < 160) {  // 64 nodes x 40 outs
        const int tj = tid % 10, tn = tid / 10;
        const int j0 = tj * 4, n0l = tn * 4;
        float acc[4][4];
#pragma unroll
        for (int i = 0; i < 4; ++i)
#pragma unroll
            for (int j = 0; j < 4; ++j) acc[i][j] = bfin[j0 + j];
        for (int k = 0; k < 64; k += 4) {
            float4 a0 = *(const float4*)&sT[n0l + 0][k];
            float4 a1 = *(const float4*)&sT[n0l + 1][k];
            float4 a2 = *(const float4*)&sT[n0l + 2][k];
            float4 a3 = *(const float4*)&sT[n0l + 3][k];
            float4 w0 = *(const float4*)&Wf[(k + 0) * 40 + j0];
            float4 w1 = *(const float4*)&Wf[(k + 1) * 40 + j0];
            float4 w2 = *(const float4*)&Wf[(k + 2) * 40 + j0];
            float4 w3 = *(const float4*)&Wf[(k + 3) * 40 + j0];
            GIN_STEP(a0, 0) GIN_STEP(a1, 1) GIN_STEP(a2, 2) GIN_STEP(a3, 3)
        }
#pragma unroll
        for (int i = 0; i < 4; ++i)
            *(float4*)&sLog[n0l + i][j0] = make_float4(acc[i][0], acc[i][1], acc[i][2], acc[i][3]);
    }
    __syncthreads();
    if (tid < 64) {
        const int nl = tid;
        const int n = base + nl;
        if (n < n_nodes) {
            float m = -1e30f;
            for (int j = 0; j < 40; ++j) m = fmaxf(m, sLog[nl][j]);
            float s = 0.f;
            for (int j = 0; j < 40; ++j) s += expf(sLog[nl][j] - m);
            float lse = m + logf(s);
            for (int j = 0; j < 40; j += 4) {
                float4 o;
                o.x = sLog[nl][j + 0] - lse;
                o.y = sLog[nl][j + 1] - lse;
                o.z = sLog[nl][j + 2] - lse;
                o.w = sLog[nl][j + 3] - lse;
                *(float4*)&out[(size_t)n * 40 + j] = o;
            }
        }
    }
}

// ============================ launch ============================

extern "C" void kernel_launch(void* const* d_in, const int* in_sizes, int n_in,
                              void* d_out, int out_size, void* d_ws, size_t ws_size,
                              hipStream_t stream) {
    const float* x  = (const float*)d_in[0];
    const int*   ei = (const int*)d_in[1];
    const float* W1 = (const float*)d_in[2];
    const float* b1 = (const float*)d_in[3];
    const float* W2 = (const float*)d_in[4];
    const float* b2 = (const float*)d_in[5];
    const float* W3 = (const float*)d_in[6];
    const float* b3 = (const float*)d_in[7];
    const float* W4 = (const float*)d_in[8];
    const float* b4 = (const float*)d_in[9];
    const float* Wf = (const float*)d_in[10];
    const float* bf = (const float*)d_in[11];
    float* outp = (float*)d_out;

    const int N = N_NODES_C, E = N_EDGES_C;
    const int* srcp = ei;
    const int* dstp = ei + E;

    // workspace layout (~65 MB)
    char* ws = (char*)d_ws;
    int*          offs  = (int*)(ws);                    // N+1 ints        -> 400128
    int*          boffs = (int*)(ws + 400128);           // NB+1 ints       -> 404352
    int*          bsums = (int*)(ws + 404352);           // 256 ints        -> 405376
    int*          cnt   = (int*)(ws + 405376);           // NB*NBLK ints    -> 1018624
    unsigned int* stage = (unsigned int*)(ws + 1018624); // E u32           -> 13818624
    int*          srcs  = (int*)(ws + 13818624);         // E ints          -> 26618624
    u16*          Ybf   = (u16*)(ws + 26618624);         // N*64 bf16       -> 39418624
    float*        F2    = (float*)(ws + 39418624);       // N*64 f32        -> 65018624

    // ---- atomic-free bucketed CSR build ----
    passA_hist_kernel<<<NBLK, 256, 0, stream>>>(dstp, cnt, E);
    const int n_scan = NB * NBLK;
    const int nblk_scan = (n_scan + 1023) / 1024;
    scan_chunks_kernel<<<nblk_scan, 256, 0, stream>>>(cnt, n_scan, bsums);
    scan_sums_kernel<<<1, 256, 0, stream>>>(bsums, nblk_scan);
    scan_add_kernel<<<nblk_scan, 256, 0, stream>>>(cnt, n_scan, bsums);
    boffs_kernel<<<1, 1024, 0, stream>>>(cnt, boffs, offs);
    passB_sort_kernel<<<NBLK, 256, 0, stream>>>(srcp, dstp, cnt, stage, E);
    bucket_finalize_kernel<<<NB, 256, 0, stream>>>(stage, boffs, offs, srcs);

    const int mlp_grid = (N + 63) / 64;
    const int gat_grid = (N + 3) / 4;

    // ---- conv1: y = bf16(x@W1); h1 = relu(y_n + sum y_src + b1); u = bf16(relu(h1@W2+b2)@W3) ----
    dense128_kernel<<<mlp_grid, 256, 0, stream>>>(x, W1, Ybf, N);
    gather64v_kernel<<<gat_grid, 256, 0, stream>>>(Ybf, offs, srcs, b1, F2, N);
    fused_w2w3_kernel<<<mlp_grid, 256, 0, stream>>>(F2, W2, b2, W3, Ybf, N);

    // ---- conv2: h3 = relu(u_n + sum u_src + b3); out = logsoftmax(relu(h3@W4+b4)@Wf + bf) ----
    gather64v_kernel<<<gat_grid, 256, 0, stream>>>(Ybf, offs, srcs, b3, F2, N);
    fused_w4final_kernel<<<mlp_grid, 256, 0, stream>>>(F2, W4, b4, Wf, bf, outp, N);
}

// Round 10
// 344.100 us; speedup vs baseline: 1.0791x; 1.0791x over previous
//
#include <hip/hip_runtime.h>
#include <math.h>

#define N_NODES_C 100000
#define N_EDGES_C 3200000
#define NB 782        // ceil(100000 / 128) buckets of 128 nodes
#define BNODES 128
#define LDS_CAP 6144  // per-bucket LDS staging capacity (mean ~4092, +32 sigma)
#define CHUNK 16384   // edges per partition block
#define NBLK 196      // ceil(N_EDGES_C / CHUNK)

typedef unsigned short u16;

__device__ __forceinline__ float bf2f(u16 u) {
    unsigned int t = ((unsigned int)u) << 16;
    return __uint_as_float(t);
}
__device__ __forceinline__ u16 f2bf(float f) {  // round-to-nearest-even
    unsigned int x = __float_as_uint(f);
    x += 0x7fffu + ((x >> 16) & 1u);
    return (u16)(x >> 16);
}

// ============================ atomic-free bucketed partition ============================

__global__ __launch_bounds__(256) void passA_hist_kernel(const int* __restrict__ dst,
                                                         int* __restrict__ cnt, int n_edges) {
    __shared__ int h[NB];
    for (int i = threadIdx.x; i < NB; i += 256) h[i] = 0;
    __syncthreads();
    const int blk = blockIdx.x;
    const int end = min((blk + 1) * CHUNK, n_edges);
    for (int e = blk * CHUNK + threadIdx.x; e < end; e += 256)
        atomicAdd(&h[dst[e] >> 7], 1);
    __syncthreads();
    for (int i = threadIdx.x; i < NB; i += 256) cnt[i * NBLK + blk] = h[i];
}

__global__ __launch_bounds__(256) void scan_chunks_kernel(int* __restrict__ a, int n, int* __restrict__ bsums) {
    __shared__ int s[256];
    const int tid = threadIdx.x;
    int base = blockIdx.x * 1024 + tid * 4;
    int v[4];
#pragma unroll
    for (int i = 0; i < 4; ++i) v[i] = (base + i < n) ? a[base + i] : 0;
    int tsum = v[0] + v[1] + v[2] + v[3];
    s[tid] = tsum;
    __syncthreads();
    for (int off = 1; off < 256; off <<= 1) {
        int t = (tid >= off) ? s[tid - off] : 0;
        __syncthreads();
        s[tid] += t;
        __syncthreads();
    }
    int run = s[tid] - tsum;
#pragma unroll
    for (int i = 0; i < 4; ++i) {
        run += v[i];
        if (base + i < n) a[base + i] = run;
    }
    if (tid == 255) bsums[blockIdx.x] = s[255];
}

__global__ __launch_bounds__(256) void scan_sums_kernel(int* __restrict__ bsums, int nb) {
    __shared__ int s[256];
    const int tid = threadIdx.x;
    int v = (tid < nb) ? bsums[tid] : 0;
    s[tid] = v;
    __syncthreads();
    for (int off = 1; off < 256; off <<= 1) {
        int t = (tid >= off) ? s[tid - off] : 0;
        __syncthreads();
        s[tid] += t;
        __syncthreads();
    }
    if (tid < nb) bsums[tid] = s[tid] - v;
}

__global__ __launch_bounds__(256) void scan_add_kernel(int* __restrict__ a, int n, const int* __restrict__ bsums) {
    int base = blockIdx.x * 1024 + threadIdx.x * 4;
    int add = bsums[blockIdx.x];
#pragma unroll
    for (int i = 0; i < 4; ++i)
        if (base + i < n) a[base + i] += add;
}

__global__ __launch_bounds__(1024) void boffs_kernel(const int* __restrict__ incl,
                                                     int* __restrict__ boffs,
                                                     int* __restrict__ offs) {
    const int b = threadIdx.x;
    if (b < NB) boffs[b] = b ? incl[b * NBLK - 1] : 0;
    if (b == 0) {
        int total = incl[NB * NBLK - 1];
        boffs[NB] = total;
        offs[N_NODES_C] = total;
    }
}

// pass B (LDS sort): block-local counting sort by bucket, then burst-write each run
__global__ __launch_bounds__(256) void passB_sort_kernel(const int* __restrict__ src,
                                                         const int* __restrict__ dst,
                                                         const int* __restrict__ incl,
                                                         unsigned int* __restrict__ stage,
                                                         int n_edges) {
    __shared__ unsigned int sdst[CHUNK];    // 64 KB
    __shared__ unsigned int spack[CHUNK];   // 64 KB
    __shared__ int hist[NB];
    __shared__ int lcur[NB];
    __shared__ int tsum[256];
    const int blk = blockIdx.x, tid = threadIdx.x;
    const int e0 = blk * CHUNK;
    const int cntE = min(CHUNK, n_edges - e0);

    for (int b = tid; b < NB; b += 256) hist[b] = 0;
    __syncthreads();

    if (cntE == CHUNK) {
        for (int i = tid * 4; i < CHUNK; i += 1024) {
            int4 d4 = *(const int4*)&dst[e0 + i];
            sdst[i + 0] = (unsigned)d4.x; sdst[i + 1] = (unsigned)d4.y;
            sdst[i + 2] = (unsigned)d4.z; sdst[i + 3] = (unsigned)d4.w;
            atomicAdd(&hist[d4.x >> 7], 1); atomicAdd(&hist[d4.y >> 7], 1);
            atomicAdd(&hist[d4.z >> 7], 1); atomicAdd(&hist[d4.w >> 7], 1);
        }
    } else {
        for (int i = tid; i < cntE; i += 256) {
            int d = dst[e0 + i];
            sdst[i] = (unsigned)d;
            atomicAdd(&hist[d >> 7], 1);
        }
    }
    __syncthreads();

    {
        int loc[4];
        const int bi = tid * 4;
        int s = 0;
#pragma unroll
        for (int k = 0; k < 4; ++k) {
            int idx = bi + k;
            loc[k] = (idx < NB) ? hist[idx] : 0;
            s += loc[k];
        }
        tsum[tid] = s;
        __syncthreads();
        for (int off = 1; off < 256; off <<= 1) {
            int t = (tid >= off) ? tsum[tid - off] : 0;
            __syncthreads();
            tsum[tid] += t;
            __syncthreads();
        }
        int run = tsum[tid] - s;
#pragma unroll
        for (int k = 0; k < 4; ++k) {
            int idx = bi + k;
            if (idx < NB) {
                int h = loc[k];
                hist[idx] = run;
                lcur[idx] = run;
                run += h;
            }
        }
    }
    __syncthreads();

    if (cntE == CHUNK) {
        for (int i = tid * 4; i < CHUNK; i += 1024) {
            int4 s4 = *(const int4*)&src[e0 + i];
            unsigned int d; int p;
            d = sdst[i + 0]; p = atomicAdd(&lcur[d >> 7], 1); spack[p] = (unsigned)s4.x | ((d & 127u) << 17);
            d = sdst[i + 1]; p = atomicAdd(&lcur[d >> 7], 1); spack[p] = (unsigned)s4.y | ((d & 127u) << 17);
            d = sdst[i + 2]; p = atomicAdd(&lcur[d >> 7], 1); spack[p] = (unsigned)s4.z | ((d & 127u) << 17);
            d = sdst[i + 3]; p = atomicAdd(&lcur[d >> 7], 1); spack[p] = (unsigned)s4.w | ((d & 127u) << 17);
        }
    } else {
        for (int i = tid; i < cntE; i += 256) {
            unsigned int d = sdst[i];
            int p = atomicAdd(&lcur[d >> 7], 1);
            spack[p] = (unsigned)src[e0 + i] | ((d & 127u) << 17);
        }
    }
    __syncthreads();

    for (int b = tid; b < NB; b += 256) {
        int l0 = hist[b];
        int l1 = (b + 1 < NB) ? hist[b + 1] : cntE;
        int idx = b * NBLK + blk;
        int g0 = idx ? incl[idx - 1] : 0;
        for (int j = l0; j < l1; ++j) stage[g0 + (j - l0)] = spack[j];
    }
}

__global__ __launch_bounds__(256) void bucket_finalize_kernel(const unsigned int* __restrict__ stage,
                                                              const int* __restrict__ boffs,
                                                              int* __restrict__ offs,
                                                              int* __restrict__ srcs) {
    __shared__ int hist[BNODES];
    __shared__ int excl[BNODES];
    __shared__ int curs[BNODES];
    __shared__ int sbuf[LDS_CAP];
    const int b = blockIdx.x, tid = threadIdx.x;
    const int base = boffs[b];
    const int count = boffs[b + 1] - base;
    const int n0 = b * BNODES;
    for (int i = tid; i < BNODES; i += 256) hist[i] = 0;
    __syncthreads();
    for (int i = tid; i < count; i += 256) {
        unsigned int w = stage[base + i];
        atomicAdd(&hist[w >> 17], 1);
    }
    __syncthreads();
    if (tid < BNODES) excl[tid] = hist[tid];
    __syncthreads();
    for (int off = 1; off < BNODES; off <<= 1) {
        int t = 0;
        if (tid < BNODES && tid >= off) t = excl[tid - off];
        __syncthreads();
        if (tid < BNODES) excl[tid] += t;
        __syncthreads();
    }
    if (tid < BNODES) {
        int ex = excl[tid] - hist[tid];
        int n = n0 + tid;
        if (n < N_NODES_C) offs[n] = base + ex;
        curs[tid] = ex;
    }
    __syncthreads();
    if (count <= LDS_CAP) {
        for (int i = tid; i < count; i += 256) {
            unsigned int w = stage[base + i];
            int p = atomicAdd(&curs[w >> 17], 1);
            sbuf[p] = (int)(w & 0x1FFFFu);
        }
        __syncthreads();
        for (int i = tid; i < count; i += 256) srcs[base + i] = sbuf[i];
    } else {
        for (int i = tid; i < count; i += 256) {
            unsigned int w = stage[base + i];
            int p = atomicAdd(&curs[w >> 17], 1);
            srcs[base + p] = (int)(w & 0x1FFFFu);
        }
    }
}

// ====== gather64v (bf16 feats): 16 lanes/row, 4 row-slots/wave, 16-row unroll ======

__global__ __launch_bounds__(256) void gather64v_kernel(const u16* __restrict__ feat,
                                                        const int* __restrict__ offs,
                                                        const int* __restrict__ srcs,
                                                        const float* __restrict__ bias,
                                                        float* __restrict__ out, int n_nodes) {
    const int wave = threadIdx.x >> 6;
    const int lane = threadIdx.x & 63;
    const int grp  = lane >> 4;
    const int cl   = lane & 15;
    const int n = blockIdx.x * 4 + wave;
    if (n >= n_nodes) return;

    float a0 = 0.f, a1 = 0.f, a2 = 0.f, a3 = 0.f;
    if (grp == 0) {
        ushort4 v = *(const ushort4*)&feat[(size_t)n * 64 + cl * 4];
        a0 = bf2f(v.x); a1 = bf2f(v.y); a2 = bf2f(v.z); a3 = bf2f(v.w);
    }
    const int s0 = offs[n], s1 = offs[n + 1];
    int i = s0;
    for (; i + 16 <= s1; i += 16) {
        int r0 = srcs[i + grp];
        int r1 = srcs[i + 4 + grp];
        int r2 = srcs[i + 8 + grp];
        int r3 = srcs[i + 12 + grp];
        ushort4 v0 = *(const ushort4*)&feat[(size_t)r0 * 64 + cl * 4];
        ushort4 v1 = *(const ushort4*)&feat[(size_t)r1 * 64 + cl * 4];
        ushort4 v2 = *(const ushort4*)&feat[(size_t)r2 * 64 + cl * 4];
        ushort4 v3 = *(const ushort4*)&feat[(size_t)r3 * 64 + cl * 4];
        a0 += bf2f(v0.x); a1 += bf2f(v0.y); a2 += bf2f(v0.z); a3 += bf2f(v0.w);
        a0 += bf2f(v1.x); a1 += bf2f(v1.y); a2 += bf2f(v1.z); a3 += bf2f(v1.w);
        a0 += bf2f(v2.x); a1 += bf2f(v2.y); a2 += bf2f(v2.z); a3 += bf2f(v2.w);
        a0 += bf2f(v3.x); a1 += bf2f(v3.y); a2 += bf2f(v3.z); a3 += bf2f(v3.w);
    }
    for (; i + 4 <= s1; i += 4) {
        int r = srcs[i + grp];
        ushort4 v = *(const ushort4*)&feat[(size_t)r * 64 + cl * 4];
        a0 += bf2f(v.x); a1 += bf2f(v.y); a2 += bf2f(v.z); a3 += bf2f(v.w);
    }
    if (i + grp < s1) {
        int r = srcs[i + grp];
        ushort4 v = *(const ushort4*)&feat[(size_t)r * 64 + cl * 4];
        a0 += bf2f(v.x); a1 += bf2f(v.y); a2 += bf2f(v.z); a3 += bf2f(v.w);
    }
    a0 += __shfl_xor(a0, 16); a1 += __shfl_xor(a1, 16);
    a2 += __shfl_xor(a2, 16); a3 += __shfl_xor(a3, 16);
    a0 += __shfl_xor(a0, 32); a1 += __shfl_xor(a1, 32);
    a2 += __shfl_xor(a2, 32); a3 += __shfl_xor(a3, 32);
    if (lane < 16) {
        float4 b = *(const float4*)&bias[cl * 4];
        float4 o;
        o.x = fmaxf(a0 + b.x, 0.f);
        o.y = fmaxf(a1 + b.y, 0.f);
        o.z = fmaxf(a2 + b.z, 0.f);
        o.w = fmaxf(a3 + b.w, 0.f);
        *(float4*)&out[(size_t)n * 64 + cl * 4] = o;
    }
}

// GEMM quad-step macro: acc[4][4] += a{0..3}.{x,y,z,w} * w{0..3}
#define GIN_STEP(ai, i)                                                                               \
    acc[i][0] += ai.x * w0.x; acc[i][1] += ai.x * w0.y; acc[i][2] += ai.x * w0.z; acc[i][3] += ai.x * w0.w; \
    acc[i][0] += ai.y * w1.x; acc[i][1] += ai.y * w1.y; acc[i][2] += ai.y * w1.z; acc[i][3] += ai.y * w1.w; \
    acc[i][0] += ai.z * w2.x; acc[i][1] += ai.z * w2.y; acc[i][2] += ai.z * w2.z; acc[i][3] += ai.z * w2.w; \
    acc[i][0] += ai.w * w3.x; acc[i][1] += ai.w * w3.y; acc[i][2] += ai.w * w3.z; acc[i][3] += ai.w * w3.w;

// ====== dense128: out_bf16 = x @ W1  (no LDS; unroll-capped to bound VGPR) ======

__global__ __launch_bounds__(256) void dense128_kernel(const float* __restrict__ in,
                                                       const float* __restrict__ W,
                                                       u16* __restrict__ out, int n_nodes) {
    const int tid = threadIdx.x;
    const int tj = tid & 15, tn = tid >> 4;
    const int j0 = tj * 4, n0 = blockIdx.x * 64 + tn * 4;
    const int r0 = min(n0 + 0, n_nodes - 1), r1 = min(n0 + 1, n_nodes - 1);
    const int r2 = min(n0 + 2, n_nodes - 1), r3 = min(n0 + 3, n_nodes - 1);
    float acc[4][4];
#pragma unroll
    for (int i = 0; i < 4; ++i)
#pragma unroll
        for (int j = 0; j < 4; ++j) acc[i][j] = 0.f;
#pragma unroll 2
    for (int k = 0; k < 128; k += 4) {
        float4 a0 = *(const float4*)&in[(size_t)r0 * 128 + k];
        float4 a1 = *(const float4*)&in[(size_t)r1 * 128 + k];
        float4 a2 = *(const float4*)&in[(size_t)r2 * 128 + k];
        float4 a3 = *(const float4*)&in[(size_t)r3 * 128 + k];
        float4 w0 = *(const float4*)&W[(k + 0) * 64 + j0];
        float4 w1 = *(const float4*)&W[(k + 1) * 64 + j0];
        float4 w2 = *(const float4*)&W[(k + 2) * 64 + j0];
        float4 w3 = *(const float4*)&W[(k + 3) * 64 + j0];
        GIN_STEP(a0, 0) GIN_STEP(a1, 1) GIN_STEP(a2, 2) GIN_STEP(a3, 3)
    }
#pragma unroll
    for (int i = 0; i < 4; ++i) {
        int n = n0 + i;
        if (n < n_nodes) {
            ushort4 o;
            o.x = f2bf(acc[i][0]); o.y = f2bf(acc[i][1]);
            o.z = f2bf(acc[i][2]); o.w = f2bf(acc[i][3]);
            *(ushort4*)&out[(size_t)n * 64 + j0] = o;
        }
    }
}

// ====== fused: T = relu(in@W2 + b2); out_bf16 = T @ W3  (sT only in LDS, unroll-capped) ======

__global__ __launch_bounds__(256) void fused_w2w3_kernel(const float* __restrict__ in,
                                                         const float* __restrict__ W2,
                                                         const float* __restrict__ b2,
                                                         const float* __restrict__ W3,
                                                         u16* __restrict__ out, int n_nodes) {
    __shared__ float sT[64][68];
    const int tid = threadIdx.x;
    const int tj = tid & 15, tn = tid >> 4;
    const int j0 = tj * 4, n0l = tn * 4;
    const int base = blockIdx.x * 64;
    const int r0 = min(base + n0l + 0, n_nodes - 1), r1 = min(base + n0l + 1, n_nodes - 1);
    const int r2 = min(base + n0l + 2, n_nodes - 1), r3 = min(base + n0l + 3, n_nodes - 1);
    float acc[4][4];
#pragma unroll
    for (int i = 0; i < 4; ++i)
#pragma unroll
        for (int j = 0; j < 4; ++j) acc[i][j] = b2[j0 + j];
#pragma unroll 2
    for (int k = 0; k < 64; k += 4) {
        float4 a0 = *(const float4*)&in[(size_t)r0 * 64 + k];
        float4 a1 = *(const float4*)&in[(size_t)r1 * 64 + k];
        float4 a2 = *(const float4*)&in[(size_t)r2 * 64 + k];
        float4 a3 = *(const float4*)&in[(size_t)r3 * 64 + k];
        float4 w0 = *(const float4*)&W2[(k + 0) * 64 + j0];
        float4 w1 = *(const float4*)&W2[(k + 1) * 64 + j0];
        float4 w2 = *(const float4*)&W2[(k + 2) * 64 + j0];
        float4 w3 = *(const float4*)&W2[(k + 3) * 64 + j0];
        GIN_STEP(a0, 0) GIN_STEP(a1, 1) GIN_STEP(a2, 2) GIN_STEP(a3, 3)
    }
#pragma unroll
    for (int i = 0; i < 4; ++i) {
        float4 t;
        t.x = fmaxf(acc[i][0], 0.f); t.y = fmaxf(acc[i][1], 0.f);
        t.z = fmaxf(acc[i][2], 0.f); t.w = fmaxf(acc[i][3], 0.f);
        *(float4*)&sT[n0l + i][j0] = t;
    }
    __syncthreads();
#pragma unroll
    for (int i = 0; i < 4; ++i)
#pragma unroll
        for (int j = 0; j < 4; ++j) acc[i][j] = 0.f;
#pragma unroll 2
    for (int k = 0; k < 64; k += 4) {
        float4 a0 = *(const float4*)&sT[n0l + 0][k];
        float4 a1 = *(const float4*)&sT[n0l + 1][k];
        float4 a2 = *(const float4*)&sT[n0l + 2][k];
        float4 a3 = *(const float4*)&sT[n0l + 3][k];
        float4 w0 = *(const float4*)&W3[(k + 0) * 64 + j0];
        float4 w1 = *(const float4*)&W3[(k + 1) * 64 + j0];
        float4 w2 = *(const float4*)&W3[(k + 2) * 64 + j0];
        float4 w3 = *(const float4*)&W3[(k + 3) * 64 + j0];
        GIN_STEP(a0, 0) GIN_STEP(a1, 1) GIN_STEP(a2, 2) GIN_STEP(a3, 3)
    }
#pragma unroll
    for (int i = 0; i < 4; ++i) {
        int n = base + n0l + i;
        if (n < n_nodes) {
            ushort4 o;
            o.x = f2bf(acc[i][0]); o.y = f2bf(acc[i][1]);
            o.z = f2bf(acc[i][2]); o.w = f2bf(acc[i][3]);
            *(ushort4*)&out[(size_t)n * 64 + j0] = o;
        }
    }
}

// ====== fused final: T = relu(in@W4+b4); logits = T@Wf+bf; out = log_softmax ======

__global__ __launch_bounds__(256) void fused_w4final_kernel(const float* __restrict__ in,
                                                            const float* __restrict__ W4,
                                                            const float* __restrict__ b4,
                                                            const float* __restrict__ Wf,
                                                            const float* __restrict__ bfin,
                                                            float* __restrict__ out, int n_nodes) {
    __shared__ float sT[64][68];
    __shared__ float sLog[64][40];
    const int tid = threadIdx.x;
    const int base = blockIdx.x * 64;
    {
        const int tj = tid & 15, tn = tid >> 4;
        const int j0 = tj * 4, n0l = tn * 4;
        const int r0 = min(base + n0l + 0, n_nodes - 1), r1 = min(base + n0l + 1, n_nodes - 1);
        const int r2 = min(base + n0l + 2, n_nodes - 1), r3 = min(base + n0l + 3, n_nodes - 1);
        float acc[4][4];
#pragma unroll
        for (int i = 0; i < 4; ++i)
#pragma unroll
            for (int j = 0; j < 4; ++j) acc[i][j] = b4[j0 + j];
#pragma unroll 2
        for (int k = 0; k < 64; k += 4) {
            float4 a0 = *(const float4*)&in[(size_t)r0 * 64 + k];
            float4 a1 = *(const float4*)&in[(size_t)r1 * 64 + k];
            float4 a2 = *(const float4*)&in[(size_t)r2 * 64 + k];
            float4 a3 = *(const float4*)&in[(size_t)r3 * 64 + k];
            float4 w0 = *(const float4*)&W4[(k + 0) * 64 + j0];
            float4 w1 = *(const float4*)&W4[(k + 1) * 64 + j0];
            float4 w2 = *(const float4*)&W4[(k + 2) * 64 + j0];
            float4 w3 = *(const float4*)&W4[(k + 3) * 64 + j0];
            GIN_STEP(a0, 0) GIN_STEP(a1, 1) GIN_STEP(a2, 2) GIN_STEP(a3, 3)
        }
#pragma unroll
        for (int i = 0; i < 4; ++i) {
            float4 t;
            t.x = fmaxf(acc[i][0], 0.f); t.y = fmaxf(acc[i][1], 0.f);
            t.z = fmaxf(acc[i][2], 0.f); t.w = fmaxf(acc[i][3], 0.f);
            *(float4*)&sT[n0l + i][j0] = t;
        }
    }
    __syncthreads();
    if (tid < 160) {  // 64 nodes x 40 outs
        const int tj = tid % 10, tn = tid / 10;
        const int j0 = tj * 4, n0l = tn * 4;
        float acc[4][4];
#pragma unroll
        for (int i = 0; i < 4; ++i)
#pragma unroll
            for (int j = 0; j < 4; ++j) acc[i][j] = bfin[j0 + j];
#pragma unroll 2
        for (int k = 0; k < 64; k += 4) {
            float4 a0 = *(const float4*)&sT[n0l + 0][k];
            float4 a1 = *(const float4*)&sT[n0l + 1][k];
            float4 a2 = *(const float4*)&sT[n0l + 2][k];
            float4 a3 = *(const float4*)&sT[n0l + 3][k];
            float4 w0 = *(const float4*)&Wf[(k + 0) * 40 + j0];
            float4 w1 = *(const float4*)&Wf[(k + 1) * 40 + j0];
            float4 w2 = *(const float4*)&Wf[(k + 2) * 40 + j0];
            float4 w3 = *(const float4*)&Wf[(k + 3) * 40 + j0];
            GIN_STEP(a0, 0) GIN_STEP(a1, 1) GIN_STEP(a2, 2) GIN_STEP(a3, 3)
        }
#pragma unroll
        for (int i = 0; i < 4; ++i)
            *(float4*)&sLog[n0l + i][j0] = make_float4(acc[i][0], acc[i][1], acc[i][2], acc[i][3]);
    }
    __syncthreads();
    if (tid < 64) {
        const int nl = tid;
        const int n = base + nl;
        if (n < n_nodes) {
            float m = -1e30f;
            for (int j = 0; j < 40; ++j) m = fmaxf(m, sLog[nl][j]);
            float s = 0.f;
            for (int j = 0; j < 40; ++j) s += expf(sLog[nl][j] - m);
            float lse = m + logf(s);
            for (int j = 0; j < 40; j += 4) {
                float4 o;
                o.x = sLog[nl][j + 0] - lse;
                o.y = sLog[nl][j + 1] - lse;
                o.z = sLog[nl][j + 2] - lse;
                o.w = sLog[nl][j + 3] - lse;
                *(float4*)&out[(size_t)n * 40 + j] = o;
            }
        }
    }
}

// ============================ launch ============================

extern "C" void kernel_launch(void* const* d_in, const int* in_sizes, int n_in,
                              void* d_out, int out_size, void* d_ws, size_t ws_size,
                              hipStream_t stream) {
    const float* x  = (const float*)d_in[0];
    const int*   ei = (const int*)d_in[1];
    const float* W1 = (const float*)d_in[2];
    const float* b1 = (const float*)d_in[3];
    const float* W2 = (const float*)d_in[4];
    const float* b2 = (const float*)d_in[5];
    const float* W3 = (const float*)d_in[6];
    const float* b3 = (const float*)d_in[7];
    const float* W4 = (const float*)d_in[8];
    const float* b4 = (const float*)d_in[9];
    const float* Wf = (const float*)d_in[10];
    const float* bf = (const float*)d_in[11];
    float* outp = (float*)d_out;

    const int N = N_NODES_C, E = N_EDGES_C;
    const int* srcp = ei;
    const int* dstp = ei + E;

    // workspace layout (~65 MB)
    char* ws = (char*)d_ws;
    int*          offs  = (int*)(ws);                    // N+1 ints        -> 400128
    int*          boffs = (int*)(ws + 400128);           // NB+1 ints       -> 404352
    int*          bsums = (int*)(ws + 404352);           // 256 ints        -> 405376
    int*          cnt   = (int*)(ws + 405376);           // NB*NBLK ints    -> 1018624
    unsigned int* stage = (unsigned int*)(ws + 1018624); // E u32           -> 13818624
    int*          srcs  = (int*)(ws + 13818624);         // E ints          -> 26618624
    u16*          Ybf   = (u16*)(ws + 26618624);         // N*64 bf16       -> 39418624
    float*        F2    = (float*)(ws + 39418624);       // N*64 f32        -> 65018624

    // ---- atomic-free bucketed CSR build ----
    passA_hist_kernel<<<NBLK, 256, 0, stream>>>(dstp, cnt, E);
    const int n_scan = NB * NBLK;
    const int nblk_scan = (n_scan + 1023) / 1024;
    scan_chunks_kernel<<<nblk_scan, 256, 0, stream>>>(cnt, n_scan, bsums);
    scan_sums_kernel<<<1, 256, 0, stream>>>(bsums, nblk_scan);
    scan_add_kernel<<<nblk_scan, 256, 0, stream>>>(cnt, n_scan, bsums);
    boffs_kernel<<<1, 1024, 0, stream>>>(cnt, boffs, offs);
    passB_sort_kernel<<<NBLK, 256, 0, stream>>>(srcp, dstp, cnt, stage, E);
    bucket_finalize_kernel<<<NB, 256, 0, stream>>>(stage, boffs, offs, srcs);

    const int mlp_grid = (N + 63) / 64;
    const int gat_grid = (N + 3) / 4;

    // ---- conv1: y = bf16(x@W1); h1 = relu(y_n + sum y_src + b1); u = bf16(relu(h1@W2+b2)@W3) ----
    dense128_kernel<<<mlp_grid, 256, 0, stream>>>(x, W1, Ybf, N);
    gather64v_kernel<<<gat_grid, 256, 0, stream>>>(Ybf, offs, srcs, b1, F2, N);
    fused_w2w3_kernel<<<mlp_grid, 256, 0, stream>>>(F2, W2, b2, W3, Ybf, N);

    // ---- conv2: h3 = relu(u_n + sum u_src + b3); out = logsoftmax(relu(h3@W4+b4)@Wf + bf) ----
    gather64v_kernel<<<gat_grid, 256, 0, stream>>>(Ybf, offs, srcs, b3, F2, N);
    fused_w4final_kernel<<<mlp_grid, 256, 0, stream>>>(F2, W4, b4, Wf, bf, outp, N);
}

// Round 11
// 301.576 us; speedup vs baseline: 1.2313x; 1.1410x over previous
//
#include <hip/hip_runtime.h>
#include <math.h>

#define N_NODES_C 100000
#define N_EDGES_C 3200000
#define NB 782        // ceil(100000 / 128) buckets of 128 nodes
#define BNODES 128
#define LDS_CAP 6144  // per-bucket LDS staging capacity (mean ~4092, +32 sigma)
#define CHUNK 16384   // edges per partition block
#define NBLK 196      // ceil(N_EDGES_C / CHUNK)

typedef unsigned short u16;

__device__ __forceinline__ float bf2f(u16 u) {
    unsigned int t = ((unsigned int)u) << 16;
    return __uint_as_float(t);
}
__device__ __forceinline__ u16 f2bf(float f) {  // round-to-nearest-even
    unsigned int x = __float_as_uint(f);
    x += 0x7fffu + ((x >> 16) & 1u);
    return (u16)(x >> 16);
}

// ============================ atomic-free bucketed partition ============================

__global__ __launch_bounds__(256) void passA_hist_kernel(const int* __restrict__ dst,
                                                         int* __restrict__ cnt, int n_edges) {
    __shared__ int h[NB];
    for (int i = threadIdx.x; i < NB; i += 256) h[i] = 0;
    __syncthreads();
    const int blk = blockIdx.x;
    const int end = min((blk + 1) * CHUNK, n_edges);
    for (int e = blk * CHUNK + threadIdx.x; e < end; e += 256)
        atomicAdd(&h[dst[e] >> 7], 1);
    __syncthreads();
    for (int i = threadIdx.x; i < NB; i += 256) cnt[i * NBLK + blk] = h[i];
}

__global__ __launch_bounds__(256) void scan_chunks_kernel(int* __restrict__ a, int n, int* __restrict__ bsums) {
    __shared__ int s[256];
    const int tid = threadIdx.x;
    int base = blockIdx.x * 1024 + tid * 4;
    int v[4];
#pragma unroll
    for (int i = 0; i < 4; ++i) v[i] = (base + i < n) ? a[base + i] : 0;
    int tsum = v[0] + v[1] + v[2] + v[3];
    s[tid] = tsum;
    __syncthreads();
    for (int off = 1; off < 256; off <<= 1) {
        int t = (tid >= off) ? s[tid - off] : 0;
        __syncthreads();
        s[tid] += t;
        __syncthreads();
    }
    int run = s[tid] - tsum;
#pragma unroll
    for (int i = 0; i < 4; ++i) {
        run += v[i];
        if (base + i < n) a[base + i] = run;
    }
    if (tid == 255) bsums[blockIdx.x] = s[255];
}

__global__ __launch_bounds__(256) void scan_sums_kernel(int* __restrict__ bsums, int nb) {
    __shared__ int s[256];
    const int tid = threadIdx.x;
    int v = (tid < nb) ? bsums[tid] : 0;
    s[tid] = v;
    __syncthreads();
    for (int off = 1; off < 256; off <<= 1) {
        int t = (tid >= off) ? s[tid - off] : 0;
        __syncthreads();
        s[tid] += t;
        __syncthreads();
    }
    if (tid < nb) bsums[tid] = s[tid] - v;
}

__global__ __launch_bounds__(256) void scan_add_kernel(int* __restrict__ a, int n, const int* __restrict__ bsums) {
    int base = blockIdx.x * 1024 + threadIdx.x * 4;
    int add = bsums[blockIdx.x];
#pragma unroll
    for (int i = 0; i < 4; ++i)
        if (base + i < n) a[base + i] += add;
}

__global__ __launch_bounds__(1024) void boffs_kernel(const int* __restrict__ incl,
                                                     int* __restrict__ boffs,
                                                     int* __restrict__ offs) {
    const int b = threadIdx.x;
    if (b < NB) boffs[b] = b ? incl[b * NBLK - 1] : 0;
    if (b == 0) {
        int total = incl[NB * NBLK - 1];
        boffs[NB] = total;
        offs[N_NODES_C] = total;
    }
}

// pass B (LDS sort): block-local counting sort by bucket, then burst-write each run
__global__ __launch_bounds__(256) void passB_sort_kernel(const int* __restrict__ src,
                                                         const int* __restrict__ dst,
                                                         const int* __restrict__ incl,
                                                         unsigned int* __restrict__ stage,
                                                         int n_edges) {
    __shared__ unsigned int sdst[CHUNK];    // 64 KB
    __shared__ unsigned int spack[CHUNK];   // 64 KB
    __shared__ int hist[NB];
    __shared__ int lcur[NB];
    __shared__ int tsum[256];
    const int blk = blockIdx.x, tid = threadIdx.x;
    const int e0 = blk * CHUNK;
    const int cntE = min(CHUNK, n_edges - e0);

    for (int b = tid; b < NB; b += 256) hist[b] = 0;
    __syncthreads();

    if (cntE == CHUNK) {
        for (int i = tid * 4; i < CHUNK; i += 1024) {
            int4 d4 = *(const int4*)&dst[e0 + i];
            sdst[i + 0] = (unsigned)d4.x; sdst[i + 1] = (unsigned)d4.y;
            sdst[i + 2] = (unsigned)d4.z; sdst[i + 3] = (unsigned)d4.w;
            atomicAdd(&hist[d4.x >> 7], 1); atomicAdd(&hist[d4.y >> 7], 1);
            atomicAdd(&hist[d4.z >> 7], 1); atomicAdd(&hist[d4.w >> 7], 1);
        }
    } else {
        for (int i = tid; i < cntE; i += 256) {
            int d = dst[e0 + i];
            sdst[i] = (unsigned)d;
            atomicAdd(&hist[d >> 7], 1);
        }
    }
    __syncthreads();

    {
        int loc[4];
        const int bi = tid * 4;
        int s = 0;
#pragma unroll
        for (int k = 0; k < 4; ++k) {
            int idx = bi + k;
            loc[k] = (idx < NB) ? hist[idx] : 0;
            s += loc[k];
        }
        tsum[tid] = s;
        __syncthreads();
        for (int off = 1; off < 256; off <<= 1) {
            int t = (tid >= off) ? tsum[tid - off] : 0;
            __syncthreads();
            tsum[tid] += t;
            __syncthreads();
        }
        int run = tsum[tid] - s;
#pragma unroll
        for (int k = 0; k < 4; ++k) {
            int idx = bi + k;
            if (idx < NB) {
                int h = loc[k];
                hist[idx] = run;
                lcur[idx] = run;
                run += h;
            }
        }
    }
    __syncthreads();

    if (cntE == CHUNK) {
        for (int i = tid * 4; i < CHUNK; i += 1024) {
            int4 s4 = *(const int4*)&src[e0 + i];
            unsigned int d; int p;
            d = sdst[i + 0]; p = atomicAdd(&lcur[d >> 7], 1); spack[p] = (unsigned)s4.x | ((d & 127u) << 17);
            d = sdst[i + 1]; p = atomicAdd(&lcur[d >> 7], 1); spack[p] = (unsigned)s4.y | ((d & 127u) << 17);
            d = sdst[i + 2]; p = atomicAdd(&lcur[d >> 7], 1); spack[p] = (unsigned)s4.z | ((d & 127u) << 17);
            d = sdst[i + 3]; p = atomicAdd(&lcur[d >> 7], 1); spack[p] = (unsigned)s4.w | ((d & 127u) << 17);
        }
    } else {
        for (int i = tid; i < cntE; i += 256) {
            unsigned int d = sdst[i];
            int p = atomicAdd(&lcur[d >> 7], 1);
            spack[p] = (unsigned)src[e0 + i] | ((d & 127u) << 17);
        }
    }
    __syncthreads();

    for (int b = tid; b < NB; b += 256) {
        int l0 = hist[b];
        int l1 = (b + 1 < NB) ? hist[b + 1] : cntE;
        int idx = b * NBLK + blk;
        int g0 = idx ? incl[idx - 1] : 0;
        for (int j = l0; j < l1; ++j) stage[g0 + (j - l0)] = spack[j];
    }
}

__global__ __launch_bounds__(256) void bucket_finalize_kernel(const unsigned int* __restrict__ stage,
                                                              const int* __restrict__ boffs,
                                                              int* __restrict__ offs,
                                                              int* __restrict__ srcs) {
    __shared__ int hist[BNODES];
    __shared__ int excl[BNODES];
    __shared__ int curs[BNODES];
    __shared__ int sbuf[LDS_CAP];
    const int b = blockIdx.x, tid = threadIdx.x;
    const int base = boffs[b];
    const int count = boffs[b + 1] - base;
    const int n0 = b * BNODES;
    for (int i = tid; i < BNODES; i += 256) hist[i] = 0;
    __syncthreads();
    for (int i = tid; i < count; i += 256) {
        unsigned int w = stage[base + i];
        atomicAdd(&hist[w >> 17], 1);
    }
    __syncthreads();
    if (tid < BNODES) excl[tid] = hist[tid];
    __syncthreads();
    for (int off = 1; off < BNODES; off <<= 1) {
        int t = 0;
        if (tid < BNODES && tid >= off) t = excl[tid - off];
        __syncthreads();
        if (tid < BNODES) excl[tid] += t;
        __syncthreads();
    }
    if (tid < BNODES) {
        int ex = excl[tid] - hist[tid];
        int n = n0 + tid;
        if (n < N_NODES_C) offs[n] = base + ex;
        curs[tid] = ex;
    }
    __syncthreads();
    if (count <= LDS_CAP) {
        for (int i = tid; i < count; i += 256) {
            unsigned int w = stage[base + i];
            int p = atomicAdd(&curs[w >> 17], 1);
            sbuf[p] = (int)(w & 0x1FFFFu);
        }
        __syncthreads();
        for (int i = tid; i < count; i += 256) srcs[base + i] = sbuf[i];
    } else {
        for (int i = tid; i < count; i += 256) {
            unsigned int w = stage[base + i];
            int p = atomicAdd(&curs[w >> 17], 1);
            srcs[base + p] = (int)(w & 0x1FFFFu);
        }
    }
}

// ====== gather64v (bf16 feats): 16 lanes/row, 4 row-slots/wave, 16-row unroll ======

__global__ __launch_bounds__(256) void gather64v_kernel(const u16* __restrict__ feat,
                                                        const int* __restrict__ offs,
                                                        const int* __restrict__ srcs,
                                                        const float* __restrict__ bias,
                                                        float* __restrict__ out, int n_nodes) {
    const int wave = threadIdx.x >> 6;
    const int lane = threadIdx.x & 63;
    const int grp  = lane >> 4;
    const int cl   = lane & 15;
    const int n = blockIdx.x * 4 + wave;
    if (n >= n_nodes) return;

    float a0 = 0.f, a1 = 0.f, a2 = 0.f, a3 = 0.f;
    if (grp == 0) {
        ushort4 v = *(const ushort4*)&feat[(size_t)n * 64 + cl * 4];
        a0 = bf2f(v.x); a1 = bf2f(v.y); a2 = bf2f(v.z); a3 = bf2f(v.w);
    }
    const int s0 = offs[n], s1 = offs[n + 1];
    int i = s0;
    for (; i + 16 <= s1; i += 16) {
        int r0 = srcs[i + grp];
        int r1 = srcs[i + 4 + grp];
        int r2 = srcs[i + 8 + grp];
        int r3 = srcs[i + 12 + grp];
        ushort4 v0 = *(const ushort4*)&feat[(size_t)r0 * 64 + cl * 4];
        ushort4 v1 = *(const ushort4*)&feat[(size_t)r1 * 64 + cl * 4];
        ushort4 v2 = *(const ushort4*)&feat[(size_t)r2 * 64 + cl * 4];
        ushort4 v3 = *(const ushort4*)&feat[(size_t)r3 * 64 + cl * 4];
        a0 += bf2f(v0.x); a1 += bf2f(v0.y); a2 += bf2f(v0.z); a3 += bf2f(v0.w);
        a0 += bf2f(v1.x); a1 += bf2f(v1.y); a2 += bf2f(v1.z); a3 += bf2f(v1.w);
        a0 += bf2f(v2.x); a1 += bf2f(v2.y); a2 += bf2f(v2.z); a3 += bf2f(v2.w);
        a0 += bf2f(v3.x); a1 += bf2f(v3.y); a2 += bf2f(v3.z); a3 += bf2f(v3.w);
    }
    for (; i + 4 <= s1; i += 4) {
        int r = srcs[i + grp];
        ushort4 v = *(const ushort4*)&feat[(size_t)r * 64 + cl * 4];
        a0 += bf2f(v.x); a1 += bf2f(v.y); a2 += bf2f(v.z); a3 += bf2f(v.w);
    }
    if (i + grp < s1) {
        int r = srcs[i + grp];
        ushort4 v = *(const ushort4*)&feat[(size_t)r * 64 + cl * 4];
        a0 += bf2f(v.x); a1 += bf2f(v.y); a2 += bf2f(v.z); a3 += bf2f(v.w);
    }
    a0 += __shfl_xor(a0, 16); a1 += __shfl_xor(a1, 16);
    a2 += __shfl_xor(a2, 16); a3 += __shfl_xor(a3, 16);
    a0 += __shfl_xor(a0, 32); a1 += __shfl_xor(a1, 32);
    a2 += __shfl_xor(a2, 32); a3 += __shfl_xor(a3, 32);
    if (lane < 16) {
        float4 b = *(const float4*)&bias[cl * 4];
        float4 o;
        o.x = fmaxf(a0 + b.x, 0.f);
        o.y = fmaxf(a1 + b.y, 0.f);
        o.z = fmaxf(a2 + b.z, 0.f);
        o.w = fmaxf(a3 + b.w, 0.f);
        *(float4*)&out[(size_t)n * 64 + cl * 4] = o;
    }
}

// GEMM quad-step macro: acc[4][4] += a{0..3}.{x,y,z,w} * w{0..3}
#define GIN_STEP(ai, i)                                                                               \
    acc[i][0] += ai.x * w0.x; acc[i][1] += ai.x * w0.y; acc[i][2] += ai.x * w0.z; acc[i][3] += ai.x * w0.w; \
    acc[i][0] += ai.y * w1.x; acc[i][1] += ai.y * w1.y; acc[i][2] += ai.y * w1.z; acc[i][3] += ai.y * w1.w; \
    acc[i][0] += ai.z * w2.x; acc[i][1] += ai.z * w2.y; acc[i][2] += ai.z * w2.z; acc[i][3] += ai.z * w2.w; \
    acc[i][0] += ai.w * w3.x; acc[i][1] += ai.w * w3.y; acc[i][2] += ai.w * w3.z; acc[i][3] += ai.w * w3.w;

// ====== dense128: out_bf16 = x @ W1  (W1 in LDS; inputs direct from global; unroll 4) ======

__global__ __launch_bounds__(256) void dense128_kernel(const float* __restrict__ in,
                                                       const float* __restrict__ W,
                                                       u16* __restrict__ out, int n_nodes) {
    __shared__ float sW[128 * 64];   // 32 KB
    const int tid = threadIdx.x;
    for (int i = tid; i < 128 * 16; i += 256) ((float4*)sW)[i] = ((const float4*)W)[i];
    __syncthreads();
    const int tj = tid & 15, tn = tid >> 4;
    const int j0 = tj * 4, n0 = blockIdx.x * 64 + tn * 4;
    const int r0 = min(n0 + 0, n_nodes - 1), r1 = min(n0 + 1, n_nodes - 1);
    const int r2 = min(n0 + 2, n_nodes - 1), r3 = min(n0 + 3, n_nodes - 1);
    float acc[4][4];
#pragma unroll
    for (int i = 0; i < 4; ++i)
#pragma unroll
        for (int j = 0; j < 4; ++j) acc[i][j] = 0.f;
#pragma unroll 4
    for (int k = 0; k < 128; k += 4) {
        float4 a0 = *(const float4*)&in[(size_t)r0 * 128 + k];
        float4 a1 = *(const float4*)&in[(size_t)r1 * 128 + k];
        float4 a2 = *(const float4*)&in[(size_t)r2 * 128 + k];
        float4 a3 = *(const float4*)&in[(size_t)r3 * 128 + k];
        float4 w0 = *(const float4*)&sW[(k + 0) * 64 + j0];
        float4 w1 = *(const float4*)&sW[(k + 1) * 64 + j0];
        float4 w2 = *(const float4*)&sW[(k + 2) * 64 + j0];
        float4 w3 = *(const float4*)&sW[(k + 3) * 64 + j0];
        GIN_STEP(a0, 0) GIN_STEP(a1, 1) GIN_STEP(a2, 2) GIN_STEP(a3, 3)
    }
#pragma unroll
    for (int i = 0; i < 4; ++i) {
        int n = n0 + i;
        if (n < n_nodes) {
            ushort4 o;
            o.x = f2bf(acc[i][0]); o.y = f2bf(acc[i][1]);
            o.z = f2bf(acc[i][2]); o.w = f2bf(acc[i][3]);
            *(ushort4*)&out[(size_t)n * 64 + j0] = o;
        }
    }
}

// ====== fused: T = relu(in@W2 + b2); out_bf16 = T @ W3  (W2,W3,sT in LDS; inputs global) ======

__global__ __launch_bounds__(256) void fused_w2w3_kernel(const float* __restrict__ in,
                                                         const float* __restrict__ W2,
                                                         const float* __restrict__ b2,
                                                         const float* __restrict__ W3,
                                                         u16* __restrict__ out, int n_nodes) {
    __shared__ float sW2[64 * 64];   // 16 KB
    __shared__ float sW3[64 * 64];   // 16 KB
    __shared__ float sT[64][68];     // 17.4 KB
    const int tid = threadIdx.x;
    for (int i = tid; i < 64 * 16; i += 256) {
        ((float4*)sW2)[i] = ((const float4*)W2)[i];
        ((float4*)sW3)[i] = ((const float4*)W3)[i];
    }
    __syncthreads();
    const int tj = tid & 15, tn = tid >> 4;
    const int j0 = tj * 4, n0l = tn * 4;
    const int base = blockIdx.x * 64;
    const int r0 = min(base + n0l + 0, n_nodes - 1), r1 = min(base + n0l + 1, n_nodes - 1);
    const int r2 = min(base + n0l + 2, n_nodes - 1), r3 = min(base + n0l + 3, n_nodes - 1);
    float acc[4][4];
#pragma unroll
    for (int i = 0; i < 4; ++i)
#pragma unroll
        for (int j = 0; j < 4; ++j) acc[i][j] = b2[j0 + j];
#pragma unroll 4
    for (int k = 0; k < 64; k += 4) {
        float4 a0 = *(const float4*)&in[(size_t)r0 * 64 + k];
        float4 a1 = *(const float4*)&in[(size_t)r1 * 64 + k];
        float4 a2 = *(const float4*)&in[(size_t)r2 * 64 + k];
        float4 a3 = *(const float4*)&in[(size_t)r3 * 64 + k];
        float4 w0 = *(const float4*)&sW2[(k + 0) * 64 + j0];
        float4 w1 = *(const float4*)&sW2[(k + 1) * 64 + j0];
        float4 w2 = *(const float4*)&sW2[(k + 2) * 64 + j0];
        float4 w3 = *(const float4*)&sW2[(k + 3) * 64 + j0];
        GIN_STEP(a0, 0) GIN_STEP(a1, 1) GIN_STEP(a2, 2) GIN_STEP(a3, 3)
    }
#pragma unroll
    for (int i = 0; i < 4; ++i) {
        float4 t;
        t.x = fmaxf(acc[i][0], 0.f); t.y = fmaxf(acc[i][1], 0.f);
        t.z = fmaxf(acc[i][2], 0.f); t.w = fmaxf(acc[i][3], 0.f);
        *(float4*)&sT[n0l + i][j0] = t;
    }
    __syncthreads();
#pragma unroll
    for (int i = 0; i < 4; ++i)
#pragma unroll
        for (int j = 0; j < 4; ++j) acc[i][j] = 0.f;
#pragma unroll 4
    for (int k = 0; k < 64; k += 4) {
        float4 a0 = *(const float4*)&sT[n0l + 0][k];
        float4 a1 = *(const float4*)&sT[n0l + 1][k];
        float4 a2 = *(const float4*)&sT[n0l + 2][k];
        float4 a3 = *(const float4*)&sT[n0l + 3][k];
        float4 w0 = *(const float4*)&sW3[(k + 0) * 64 + j0];
        float4 w1 = *(const float4*)&sW3[(k + 1) * 64 + j0];
        float4 w2 = *(const float4*)&sW3[(k + 2) * 64 + j0];
        float4 w3 = *(const float4*)&sW3[(k + 3) * 64 + j0];
        GIN_STEP(a0, 0) GIN_STEP(a1, 1) GIN_STEP(a2, 2) GIN_STEP(a3, 3)
    }
#pragma unroll
    for (int i = 0; i < 4; ++i) {
        int n = base + n0l + i;
        if (n < n_nodes) {
            ushort4 o;
            o.x = f2bf(acc[i][0]); o.y = f2bf(acc[i][1]);
            o.z = f2bf(acc[i][2]); o.w = f2bf(acc[i][3]);
            *(ushort4*)&out[(size_t)n * 64 + j0] = o;
        }
    }
}

// ====== fused final: T = relu(in@W4+b4); logits = T@Wf+bf; out = log_softmax ======
// manual smem layout; sLog aliases dead sW4 space -> 44 KB total

__global__ __launch_bounds__(256) void fused_w4final_kernel(const float* __restrict__ in,
                                                            const float* __restrict__ W4,
                                                            const float* __restrict__ b4,
                                                            const float* __restrict__ Wf,
                                                            const float* __restrict__ bfin,
                                                            float* __restrict__ out, int n_nodes) {
    __shared__ float smem[11008];            // 43 KB: [0,4096)=sW4 ; [4096,6656)=sWf ; [6656,11008)=sT[64][68]
    float* sW4 = smem;
    float* sWf = smem + 4096;
    float* sTf = smem + 6656;                // stride 68
    float* sLog = smem;                      // aliases sW4 (dead after GEMM1); 64*40=2560 <= 4096
    const int tid = threadIdx.x;
    const int base = blockIdx.x * 64;
    for (int i = tid; i < 64 * 16; i += 256) ((float4*)sW4)[i] = ((const float4*)W4)[i];
    for (int i = tid; i < 64 * 10; i += 256) ((float4*)sWf)[i] = ((const float4*)Wf)[i];
    __syncthreads();
    {
        const int tj = tid & 15, tn = tid >> 4;
        const int j0 = tj * 4, n0l = tn * 4;
        const int r0 = min(base + n0l + 0, n_nodes - 1), r1 = min(base + n0l + 1, n_nodes - 1);
        const int r2 = min(base + n0l + 2, n_nodes - 1), r3 = min(base + n0l + 3, n_nodes - 1);
        float acc[4][4];
#pragma unroll
        for (int i = 0; i < 4; ++i)
#pragma unroll
            for (int j = 0; j < 4; ++j) acc[i][j] = b4[j0 + j];
#pragma unroll 4
        for (int k = 0; k < 64; k += 4) {
            float4 a0 = *(const float4*)&in[(size_t)r0 * 64 + k];
            float4 a1 = *(const float4*)&in[(size_t)r1 * 64 + k];
            float4 a2 = *(const float4*)&in[(size_t)r2 * 64 + k];
            float4 a3 = *(const float4*)&in[(size_t)r3 * 64 + k];
            float4 w0 = *(const float4*)&sW4[(k + 0) * 64 + j0];
            float4 w1 = *(const float4*)&sW4[(k + 1) * 64 + j0];
            float4 w2 = *(const float4*)&sW4[(k + 2) * 64 + j0];
            float4 w3 = *(const float4*)&sW4[(k + 3) * 64 + j0];
            GIN_STEP(a0, 0) GIN_STEP(a1, 1) GIN_STEP(a2, 2) GIN_STEP(a3, 3)
        }
#pragma unroll
        for (int i = 0; i < 4; ++i) {
            float4 t;
            t.x = fmaxf(acc[i][0], 0.f); t.y = fmaxf(acc[i][1], 0.f);
            t.z = fmaxf(acc[i][2], 0.f); t.w = fmaxf(acc[i][3], 0.f);
            *(float4*)&sTf[(n0l + i) * 68 + j0] = t;
        }
    }
    __syncthreads();      // sT ready; sW4 now dead -> sLog may overwrite
    if (tid < 160) {      // 64 nodes x 40 outs
        const int tj = tid % 10, tn = tid / 10;
        const int j0 = tj * 4, n0l = tn * 4;
        float acc[4][4];
#pragma unroll
        for (int i = 0; i < 4; ++i)
#pragma unroll
            for (int j = 0; j < 4; ++j) acc[i][j] = bfin[j0 + j];
#pragma unroll 4
        for (int k = 0; k < 64; k += 4) {
            float4 a0 = *(const float4*)&sTf[(n0l + 0) * 68 + k];
            float4 a1 = *(const float4*)&sTf[(n0l + 1) * 68 + k];
            float4 a2 = *(const float4*)&sTf[(n0l + 2) * 68 + k];
            float4 a3 = *(const float4*)&sTf[(n0l + 3) * 68 + k];
            float4 w0 = *(const float4*)&sWf[(k + 0) * 40 + j0];
            float4 w1 = *(const float4*)&sWf[(k + 1) * 40 + j0];
            float4 w2 = *(const float4*)&sWf[(k + 2) * 40 + j0];
            float4 w3 = *(const float4*)&sWf[(k + 3) * 40 + j0];
            GIN_STEP(a0, 0) GIN_STEP(a1, 1) GIN_STEP(a2, 2) GIN_STEP(a3, 3)
        }
#pragma unroll
        for (int i = 0; i < 4; ++i)
            *(float4*)&sLog[(n0l + i) * 40 + j0] = make_float4(acc[i][0], acc[i][1], acc[i][2], acc[i][3]);
    }
    __syncthreads();
    if (tid < 64) {
        const int nl = tid;
        const int n = base + nl;
        if (n < n_nodes) {
            float m = -1e30f;
            for (int j = 0; j < 40; ++j) m = fmaxf(m, sLog[nl * 40 + j]);
            float s = 0.f;
            for (int j = 0; j < 40; ++j) s += expf(sLog[nl * 40 + j] - m);
            float lse = m + logf(s);
            for (int j = 0; j < 40; j += 4) {
                float4 o;
                o.x = sLog[nl * 40 + j + 0] - lse;
                o.y = sLog[nl * 40 + j + 1] - lse;
                o.z = sLog[nl * 40 + j + 2] - lse;
                o.w = sLog[nl * 40 + j + 3] - lse;
                *(float4*)&out[(size_t)n * 40 + j] = o;
            }
        }
    }
}

// ============================ launch ============================

extern "C" void kernel_launch(void* const* d_in, const int* in_sizes, int n_in,
                              void* d_out, int out_size, void* d_ws, size_t ws_size,
                              hipStream_t stream) {
    const float* x  = (const float*)d_in[0];
    const int*   ei = (const int*)d_in[1];
    const float* W1 = (const float*)d_in[2];
    const float* b1 = (const float*)d_in[3];
    const float* W2 = (const float*)d_in[4];
    const float* b2 = (const float*)d_in[5];
    const float* W3 = (const float*)d_in[6];
    const float* b3 = (const float*)d_in[7];
    const float* W4 = (const float*)d_in[8];
    const float* b4 = (const float*)d_in[9];
    const float* Wf = (const float*)d_in[10];
    const float* bf = (const float*)d_in[11];
    float* outp = (float*)d_out;

    const int N = N_NODES_C, E = N_EDGES_C;
    const int* srcp = ei;
    const int* dstp = ei + E;

    // workspace layout (~65 MB)
    char* ws = (char*)d_ws;
    int*          offs  = (int*)(ws);                    // N+1 ints        -> 400128
    int*          boffs = (int*)(ws + 400128);           // NB+1 ints       -> 404352
    int*          bsums = (int*)(ws + 404352);           // 256 ints        -> 405376
    int*          cnt   = (int*)(ws + 405376);           // NB*NBLK ints    -> 1018624
    unsigned int* stage = (unsigned int*)(ws + 1018624); // E u32           -> 13818624
    int*          srcs  = (int*)(ws + 13818624);         // E ints          -> 26618624
    u16*          Ybf   = (u16*)(ws + 26618624);         // N*64 bf16       -> 39418624
    float*        F2    = (float*)(ws + 39418624);       // N*64 f32        -> 65018624

    // ---- atomic-free bucketed CSR build ----
    passA_hist_kernel<<<NBLK, 256, 0, stream>>>(dstp, cnt, E);
    const int n_scan = NB * NBLK;
    const int nblk_scan = (n_scan + 1023) / 1024;
    scan_chunks_kernel<<<nblk_scan, 256, 0, stream>>>(cnt, n_scan, bsums);
    scan_sums_kernel<<<1, 256, 0, stream>>>(bsums, nblk_scan);
    scan_add_kernel<<<nblk_scan, 256, 0, stream>>>(cnt, n_scan, bsums);
    boffs_kernel<<<1, 1024, 0, stream>>>(cnt, boffs, offs);
    passB_sort_kernel<<<NBLK, 256, 0, stream>>>(srcp, dstp, cnt, stage, E);
    bucket_finalize_kernel<<<NB, 256, 0, stream>>>(stage, boffs, offs, srcs);

    const int mlp_grid = (N + 63) / 64;
    const int gat_grid = (N + 3) / 4;

    // ---- conv1: y = bf16(x@W1); h1 = relu(y_n + sum y_src + b1); u = bf16(relu(h1@W2+b2)@W3) ----
    dense128_kernel<<<mlp_grid, 256, 0, stream>>>(x, W1, Ybf, N);
    gather64v_kernel<<<gat_grid, 256, 0, stream>>>(Ybf, offs, srcs, b1, F2, N);
    fused_w2w3_kernel<<<mlp_grid, 256, 0, stream>>>(F2, W2, b2, W3, Ybf, N);

    // ---- conv2: h3 = relu(u_n + sum u_src + b3); out = logsoftmax(relu(h3@W4+b4)@Wf + bf) ----
    gather64v_kernel<<<gat_grid, 256, 0, stream>>>(Ybf, offs, srcs, b3, F2, N);
    fused_w4final_kernel<<<mlp_grid, 256, 0, stream>>>(F2, W4, b4, Wf, bf, outp, N);
}

// Round 12
// 289.122 us; speedup vs baseline: 1.2843x; 1.0431x over previous
//
#include <hip/hip_runtime.h>
#include <math.h>

#define N_NODES_C 100000
#define N_EDGES_C 3200000
#define NB 782        // ceil(100000 / 128) buckets of 128 nodes
#define BNODES 128
#define LDS_CAP 6144  // per-bucket LDS staging capacity (mean ~4092, +32 sigma)
#define CHUNK 8192    // edges per partition block
#define NBLK 391      // ceil(N_EDGES_C / CHUNK)

typedef unsigned short u16;

__device__ __forceinline__ float bf2f(u16 u) {
    unsigned int t = ((unsigned int)u) << 16;
    return __uint_as_float(t);
}
__device__ __forceinline__ u16 f2bf(float f) {  // round-to-nearest-even
    unsigned int x = __float_as_uint(f);
    x += 0x7fffu + ((x >> 16) & 1u);
    return (u16)(x >> 16);
}

// ============================ atomic-free bucketed partition ============================

__global__ __launch_bounds__(256) void passA_hist_kernel(const int* __restrict__ dst,
                                                         int* __restrict__ cnt, int n_edges) {
    __shared__ int h[NB];
    for (int i = threadIdx.x; i < NB; i += 256) h[i] = 0;
    __syncthreads();
    const int blk = blockIdx.x;
    const int e0 = blk * CHUNK;
    const int cntE = min(CHUNK, n_edges - e0);
    for (int i = threadIdx.x * 4; i < cntE; i += 1024) {
        int4 d4 = *(const int4*)&dst[e0 + i];
        atomicAdd(&h[d4.x >> 7], 1); atomicAdd(&h[d4.y >> 7], 1);
        atomicAdd(&h[d4.z >> 7], 1); atomicAdd(&h[d4.w >> 7], 1);
    }
    __syncthreads();
    for (int i = threadIdx.x; i < NB; i += 256) cnt[i * NBLK + blk] = h[i];
}

__global__ __launch_bounds__(256) void scan_chunks_kernel(int* __restrict__ a, int n, int* __restrict__ bsums) {
    __shared__ int s[256];
    const int tid = threadIdx.x;
    int base = blockIdx.x * 1024 + tid * 4;
    int v[4];
#pragma unroll
    for (int i = 0; i < 4; ++i) v[i] = (base + i < n) ? a[base + i] : 0;
    int tsum = v[0] + v[1] + v[2] + v[3];
    s[tid] = tsum;
    __syncthreads();
    for (int off = 1; off < 256; off <<= 1) {
        int t = (tid >= off) ? s[tid - off] : 0;
        __syncthreads();
        s[tid] += t;
        __syncthreads();
    }
    int run = s[tid] - tsum;
#pragma unroll
    for (int i = 0; i < 4; ++i) {
        run += v[i];
        if (base + i < n) a[base + i] = run;
    }
    if (tid == 255) bsums[blockIdx.x] = s[255];
}

// exclusive scan of bsums[0..nb), nb <= 512, single block of 512
__global__ __launch_bounds__(512) void scan_sums_kernel(int* __restrict__ bsums, int nb) {
    __shared__ int s[512];
    const int tid = threadIdx.x;
    int v = (tid < nb) ? bsums[tid] : 0;
    s[tid] = v;
    __syncthreads();
    for (int off = 1; off < 512; off <<= 1) {
        int t = (tid >= off) ? s[tid - off] : 0;
        __syncthreads();
        s[tid] += t;
        __syncthreads();
    }
    if (tid < nb) bsums[tid] = s[tid] - v;
}

__global__ __launch_bounds__(256) void scan_add_kernel(int* __restrict__ a, int n, const int* __restrict__ bsums) {
    int base = blockIdx.x * 1024 + threadIdx.x * 4;
    int add = bsums[blockIdx.x];
#pragma unroll
    for (int i = 0; i < 4; ++i)
        if (base + i < n) a[base + i] += add;
}

__global__ __launch_bounds__(1024) void boffs_kernel(const int* __restrict__ incl,
                                                     int* __restrict__ boffs,
                                                     int* __restrict__ offs) {
    const int b = threadIdx.x;
    if (b < NB) boffs[b] = b ? incl[b * NBLK - 1] : 0;
    if (b == 0) {
        int total = incl[NB * NBLK - 1];
        boffs[NB] = total;
        offs[N_NODES_C] = total;
    }
}

// pass B (LDS sort, no dst staging): counting sort by bucket, then burst-write each run
__global__ __launch_bounds__(256) void passB_sort_kernel(const int* __restrict__ src,
                                                         const int* __restrict__ dst,
                                                         const int* __restrict__ incl,
                                                         unsigned int* __restrict__ stage,
                                                         int n_edges) {
    __shared__ unsigned int spack[CHUNK];   // 32 KB
    __shared__ int hist[NB];
    __shared__ int lcur[NB];
    __shared__ int tsum[256];
    const int blk = blockIdx.x, tid = threadIdx.x;
    const int e0 = blk * CHUNK;
    const int cntE = min(CHUNK, n_edges - e0);

    for (int b = tid; b < NB; b += 256) hist[b] = 0;
    __syncthreads();

    // P1: histogram (dst read 1, L2-warm for P3)
    for (int i = tid * 4; i < cntE; i += 1024) {
        int4 d4 = *(const int4*)&dst[e0 + i];
        atomicAdd(&hist[d4.x >> 7], 1); atomicAdd(&hist[d4.y >> 7], 1);
        atomicAdd(&hist[d4.z >> 7], 1); atomicAdd(&hist[d4.w >> 7], 1);
    }
    __syncthreads();

    // P2: block-exclusive scan of hist -> hist = lbase, lcur = lbase
    {
        int loc[4];
        const int bi = tid * 4;
        int s = 0;
#pragma unroll
        for (int k = 0; k < 4; ++k) {
            int idx = bi + k;
            loc[k] = (idx < NB) ? hist[idx] : 0;
            s += loc[k];
        }
        tsum[tid] = s;
        __syncthreads();
        for (int off = 1; off < 256; off <<= 1) {
            int t = (tid >= off) ? tsum[tid - off] : 0;
            __syncthreads();
            tsum[tid] += t;
            __syncthreads();
        }
        int run = tsum[tid] - s;
#pragma unroll
        for (int k = 0; k < 4; ++k) {
            int idx = bi + k;
            if (idx < NB) {
                int h = loc[k];
                hist[idx] = run;
                lcur[idx] = run;
                run += h;
            }
        }
    }
    __syncthreads();

    // P3: re-read dst (L2-hot) + src, scatter into spack sorted by bucket
    for (int i = tid * 4; i < cntE; i += 1024) {
        int4 d4 = *(const int4*)&dst[e0 + i];
        int4 s4 = *(const int4*)&src[e0 + i];
        int p;
        p = atomicAdd(&lcur[d4.x >> 7], 1); spack[p] = (unsigned)s4.x | (((unsigned)d4.x & 127u) << 17);
        p = atomicAdd(&lcur[d4.y >> 7], 1); spack[p] = (unsigned)s4.y | (((unsigned)d4.y & 127u) << 17);
        p = atomicAdd(&lcur[d4.z >> 7], 1); spack[p] = (unsigned)s4.z | (((unsigned)d4.z & 127u) << 17);
        p = atomicAdd(&lcur[d4.w >> 7], 1); spack[p] = (unsigned)s4.w | (((unsigned)d4.w & 127u) << 17);
    }
    __syncthreads();

    // P4: burst-write each bucket run to its reserved global range
    for (int b = tid; b < NB; b += 256) {
        int l0 = hist[b];
        int l1 = (b + 1 < NB) ? hist[b + 1] : cntE;
        int idx = b * NBLK + blk;
        int g0 = idx ? incl[idx - 1] : 0;
        for (int j = l0; j < l1; ++j) stage[g0 + (j - l0)] = spack[j];
    }
}

__global__ __launch_bounds__(256) void bucket_finalize_kernel(const unsigned int* __restrict__ stage,
                                                              const int* __restrict__ boffs,
                                                              int* __restrict__ offs,
                                                              int* __restrict__ srcs) {
    __shared__ int hist[BNODES];
    __shared__ int excl[BNODES];
    __shared__ int curs[BNODES];
    __shared__ int sbuf[LDS_CAP];
    const int b = blockIdx.x, tid = threadIdx.x;
    const int base = boffs[b];
    const int count = boffs[b + 1] - base;
    const int n0 = b * BNODES;
    for (int i = tid; i < BNODES; i += 256) hist[i] = 0;
    __syncthreads();
    for (int i = tid; i < count; i += 256) {
        unsigned int w = stage[base + i];
        atomicAdd(&hist[w >> 17], 1);
    }
    __syncthreads();
    if (tid < BNODES) excl[tid] = hist[tid];
    __syncthreads();
    for (int off = 1; off < BNODES; off <<= 1) {
        int t = 0;
        if (tid < BNODES && tid >= off) t = excl[tid - off];
        __syncthreads();
        if (tid < BNODES) excl[tid] += t;
        __syncthreads();
    }
    if (tid < BNODES) {
        int ex = excl[tid] - hist[tid];
        int n = n0 + tid;
        if (n < N_NODES_C) offs[n] = base + ex;
        curs[tid] = ex;
    }
    __syncthreads();
    if (count <= LDS_CAP) {
        for (int i = tid; i < count; i += 256) {
            unsigned int w = stage[base + i];
            int p = atomicAdd(&curs[w >> 17], 1);
            sbuf[p] = (int)(w & 0x1FFFFu);
        }
        __syncthreads();
        for (int i = tid; i < count; i += 256) srcs[base + i] = sbuf[i];
    } else {
        for (int i = tid; i < count; i += 256) {
            unsigned int w = stage[base + i];
            int p = atomicAdd(&curs[w >> 17], 1);
            srcs[base + p] = (int)(w & 0x1FFFFu);
        }
    }
}

// ====== gather64v: bf16 in, bf16 out; 16 lanes/row, 4 row-slots/wave, 32-row unroll ======

__global__ __launch_bounds__(256) void gather64v_kernel(const u16* __restrict__ feat,
                                                        const int* __restrict__ offs,
                                                        const int* __restrict__ srcs,
                                                        const float* __restrict__ bias,
                                                        u16* __restrict__ out, int n_nodes) {
    const int wave = threadIdx.x >> 6;
    const int lane = threadIdx.x & 63;
    const int grp  = lane >> 4;
    const int cl   = lane & 15;
    const int n = blockIdx.x * 4 + wave;
    if (n >= n_nodes) return;

    float a0 = 0.f, a1 = 0.f, a2 = 0.f, a3 = 0.f;
    if (grp == 0) {
        ushort4 v = *(const ushort4*)&feat[(size_t)n * 64 + cl * 4];
        a0 = bf2f(v.x); a1 = bf2f(v.y); a2 = bf2f(v.z); a3 = bf2f(v.w);
    }
    const int s0 = offs[n], s1 = offs[n + 1];
    int i = s0;
    for (; i + 32 <= s1; i += 32) {  // 32 rows/iter: 8 independent feat loads per lane
        int r[8];
#pragma unroll
        for (int u = 0; u < 8; ++u) r[u] = srcs[i + u * 4 + grp];
        ushort4 v[8];
#pragma unroll
        for (int u = 0; u < 8; ++u) v[u] = *(const ushort4*)&feat[(size_t)r[u] * 64 + cl * 4];
#pragma unroll
        for (int u = 0; u < 8; ++u) {
            a0 += bf2f(v[u].x); a1 += bf2f(v[u].y); a2 += bf2f(v[u].z); a3 += bf2f(v[u].w);
        }
    }
    for (; i + 8 <= s1; i += 8) {
        int ra = srcs[i + grp];
        int rb = srcs[i + 4 + grp];
        ushort4 va = *(const ushort4*)&feat[(size_t)ra * 64 + cl * 4];
        ushort4 vb = *(const ushort4*)&feat[(size_t)rb * 64 + cl * 4];
        a0 += bf2f(va.x); a1 += bf2f(va.y); a2 += bf2f(va.z); a3 += bf2f(va.w);
        a0 += bf2f(vb.x); a1 += bf2f(vb.y); a2 += bf2f(vb.z); a3 += bf2f(vb.w);
    }
    for (; i + 4 <= s1; i += 4) {
        int rr = srcs[i + grp];
        ushort4 v = *(const ushort4*)&feat[(size_t)rr * 64 + cl * 4];
        a0 += bf2f(v.x); a1 += bf2f(v.y); a2 += bf2f(v.z); a3 += bf2f(v.w);
    }
    if (i + grp < s1) {
        int rr = srcs[i + grp];
        ushort4 v = *(const ushort4*)&feat[(size_t)rr * 64 + cl * 4];
        a0 += bf2f(v.x); a1 += bf2f(v.y); a2 += bf2f(v.z); a3 += bf2f(v.w);
    }
    a0 += __shfl_xor(a0, 16); a1 += __shfl_xor(a1, 16);
    a2 += __shfl_xor(a2, 16); a3 += __shfl_xor(a3, 16);
    a0 += __shfl_xor(a0, 32); a1 += __shfl_xor(a1, 32);
    a2 += __shfl_xor(a2, 32); a3 += __shfl_xor(a3, 32);
    if (lane < 16) {
        float4 b = *(const float4*)&bias[cl * 4];
        ushort4 o;
        o.x = f2bf(fmaxf(a0 + b.x, 0.f));
        o.y = f2bf(fmaxf(a1 + b.y, 0.f));
        o.z = f2bf(fmaxf(a2 + b.z, 0.f));
        o.w = f2bf(fmaxf(a3 + b.w, 0.f));
        *(ushort4*)&out[(size_t)n * 64 + cl * 4] = o;
    }
}

// GEMM quad-step macro: acc[4][4] += a{0..3}.{x,y,z,w} * w{0..3}
#define GIN_STEP(ai, i)                                                                               \
    acc[i][0] += ai.x * w0.x; acc[i][1] += ai.x * w0.y; acc[i][2] += ai.x * w0.z; acc[i][3] += ai.x * w0.w; \
    acc[i][0] += ai.y * w1.x; acc[i][1] += ai.y * w1.y; acc[i][2] += ai.y * w1.z; acc[i][3] += ai.y * w1.w; \
    acc[i][0] += ai.z * w2.x; acc[i][1] += ai.z * w2.y; acc[i][2] += ai.z * w2.z; acc[i][3] += ai.z * w2.w; \
    acc[i][0] += ai.w * w3.x; acc[i][1] += ai.w * w3.y; acc[i][2] += ai.w * w3.z; acc[i][3] += ai.w * w3.w;

#define BF4_TO_F4(u4) make_float4(bf2f(u4.x), bf2f(u4.y), bf2f(u4.z), bf2f(u4.w))

// ====== dense128: out_bf16 = x @ W1  (W1 in LDS; inputs direct from global; unroll 4) ======

__global__ __launch_bounds__(256) void dense128_kernel(const float* __restrict__ in,
                                                       const float* __restrict__ W,
                                                       u16* __restrict__ out, int n_nodes) {
    __shared__ float sW[128 * 64];   // 32 KB
    const int tid = threadIdx.x;
    for (int i = tid; i < 128 * 16; i += 256) ((float4*)sW)[i] = ((const float4*)W)[i];
    __syncthreads();
    const int tj = tid & 15, tn = tid >> 4;
    const int j0 = tj * 4, n0 = blockIdx.x * 64 + tn * 4;
    const int r0 = min(n0 + 0, n_nodes - 1), r1 = min(n0 + 1, n_nodes - 1);
    const int r2 = min(n0 + 2, n_nodes - 1), r3 = min(n0 + 3, n_nodes - 1);
    float acc[4][4];
#pragma unroll
    for (int i = 0; i < 4; ++i)
#pragma unroll
        for (int j = 0; j < 4; ++j) acc[i][j] = 0.f;
#pragma unroll 4
    for (int k = 0; k < 128; k += 4) {
        float4 a0 = *(const float4*)&in[(size_t)r0 * 128 + k];
        float4 a1 = *(const float4*)&in[(size_t)r1 * 128 + k];
        float4 a2 = *(const float4*)&in[(size_t)r2 * 128 + k];
        float4 a3 = *(const float4*)&in[(size_t)r3 * 128 + k];
        float4 w0 = *(const float4*)&sW[(k + 0) * 64 + j0];
        float4 w1 = *(const float4*)&sW[(k + 1) * 64 + j0];
        float4 w2 = *(const float4*)&sW[(k + 2) * 64 + j0];
        float4 w3 = *(const float4*)&sW[(k + 3) * 64 + j0];
        GIN_STEP(a0, 0) GIN_STEP(a1, 1) GIN_STEP(a2, 2) GIN_STEP(a3, 3)
    }
#pragma unroll
    for (int i = 0; i < 4; ++i) {
        int n = n0 + i;
        if (n < n_nodes) {
            ushort4 o;
            o.x = f2bf(acc[i][0]); o.y = f2bf(acc[i][1]);
            o.z = f2bf(acc[i][2]); o.w = f2bf(acc[i][3]);
            *(ushort4*)&out[(size_t)n * 64 + j0] = o;
        }
    }
}

// ====== fused: T = relu(in_bf16@W2 + b2); out_bf16 = T @ W3  (W2,W3,sT in LDS) ======

__global__ __launch_bounds__(256) void fused_w2w3_kernel(const u16* __restrict__ in,
                                                         const float* __restrict__ W2,
                                                         const float* __restrict__ b2,
                                                         const float* __restrict__ W3,
                                                         u16* __restrict__ out, int n_nodes) {
    __shared__ float sW2[64 * 64];   // 16 KB
    __shared__ float sW3[64 * 64];   // 16 KB
    __shared__ float sT[64][68];     // 17.4 KB
    const int tid = threadIdx.x;
    for (int i = tid; i < 64 * 16; i += 256) {
        ((float4*)sW2)[i] = ((const float4*)W2)[i];
        ((float4*)sW3)[i] = ((const float4*)W3)[i];
    }
    __syncthreads();
    const int tj = tid & 15, tn = tid >> 4;
    const int j0 = tj * 4, n0l = tn * 4;
    const int base = blockIdx.x * 64;
    const int r0 = min(base + n0l + 0, n_nodes - 1), r1 = min(base + n0l + 1, n_nodes - 1);
    const int r2 = min(base + n0l + 2, n_nodes - 1), r3 = min(base + n0l + 3, n_nodes - 1);
    float acc[4][4];
#pragma unroll
    for (int i = 0; i < 4; ++i)
#pragma unroll
        for (int j = 0; j < 4; ++j) acc[i][j] = b2[j0 + j];
#pragma unroll 4
    for (int k = 0; k < 64; k += 4) {
        ushort4 u0 = *(const ushort4*)&in[(size_t)r0 * 64 + k];
        ushort4 u1 = *(const ushort4*)&in[(size_t)r1 * 64 + k];
        ushort4 u2 = *(const ushort4*)&in[(size_t)r2 * 64 + k];
        ushort4 u3 = *(const ushort4*)&in[(size_t)r3 * 64 + k];
        float4 a0 = BF4_TO_F4(u0);
        float4 a1 = BF4_TO_F4(u1);
        float4 a2 = BF4_TO_F4(u2);
        float4 a3 = BF4_TO_F4(u3);
        float4 w0 = *(const float4*)&sW2[(k + 0) * 64 + j0];
        float4 w1 = *(const float4*)&sW2[(k + 1) * 64 + j0];
        float4 w2 = *(const float4*)&sW2[(k + 2) * 64 + j0];
        float4 w3 = *(const float4*)&sW2[(k + 3) * 64 + j0];
        GIN_STEP(a0, 0) GIN_STEP(a1, 1) GIN_STEP(a2, 2) GIN_STEP(a3, 3)
    }
#pragma unroll
    for (int i = 0; i < 4; ++i) {
        float4 t;
        t.x = fmaxf(acc[i][0], 0.f); t.y = fmaxf(acc[i][1], 0.f);
        t.z = fmaxf(acc[i][2], 0.f); t.w = fmaxf(acc[i][3], 0.f);
        *(float4*)&sT[n0l + i][j0] = t;
    }
    __syncthreads();
#pragma unroll
    for (int i = 0; i < 4; ++i)
#pragma unroll
        for (int j = 0; j < 4; ++j) acc[i][j] = 0.f;
#pragma unroll 4
    for (int k = 0; k < 64; k += 4) {
        float4 a0 = *(const float4*)&sT[n0l + 0][k];
        float4 a1 = *(const float4*)&sT[n0l + 1][k];
        float4 a2 = *(const float4*)&sT[n0l + 2][k];
        float4 a3 = *(const float4*)&sT[n0l + 3][k];
        float4 w0 = *(const float4*)&sW3[(k + 0) * 64 + j0];
        float4 w1 = *(const float4*)&sW3[(k + 1) * 64 + j0];
        float4 w2 = *(const float4*)&sW3[(k + 2) * 64 + j0];
        float4 w3 = *(const float4*)&sW3[(k + 3) * 64 + j0];
        GIN_STEP(a0, 0) GIN_STEP(a1, 1) GIN_STEP(a2, 2) GIN_STEP(a3, 3)
    }
#pragma unroll
    for (int i = 0; i < 4; ++i) {
        int n = base + n0l + i;
        if (n < n_nodes) {
            ushort4 o;
            o.x = f2bf(acc[i][0]); o.y = f2bf(acc[i][1]);
            o.z = f2bf(acc[i][2]); o.w = f2bf(acc[i][3]);
            *(ushort4*)&out[(size_t)n * 64 + j0] = o;
        }
    }
}

// ====== fused final: T = relu(in_bf16@W4+b4); logits = T@Wf+bf; out = log_softmax ======
// manual smem layout; sLog aliases dead sW4 space -> 43 KB total

__global__ __launch_bounds__(256) void fused_w4final_kernel(const u16* __restrict__ in,
                                                            const float* __restrict__ W4,
                                                            const float* __restrict__ b4,
                                                            const float* __restrict__ Wf,
                                                            const float* __restrict__ bfin,
                                                            float* __restrict__ out, int n_nodes) {
    __shared__ float smem[11008];            // [0,4096)=sW4 ; [4096,6656)=sWf ; [6656,11008)=sT[64][68]
    float* sW4 = smem;
    float* sWf = smem + 4096;
    float* sTf = smem + 6656;                // stride 68
    float* sLog = smem;                      // aliases sW4 (dead after GEMM1)
    const int tid = threadIdx.x;
    const int base = blockIdx.x * 64;
    for (int i = tid; i < 64 * 16; i += 256) ((float4*)sW4)[i] = ((const float4*)W4)[i];
    for (int i = tid; i < 64 * 10; i += 256) ((float4*)sWf)[i] = ((const float4*)Wf)[i];
    __syncthreads();
    {
        const int tj = tid & 15, tn = tid >> 4;
        const int j0 = tj * 4, n0l = tn * 4;
        const int r0 = min(base + n0l + 0, n_nodes - 1), r1 = min(base + n0l + 1, n_nodes - 1);
        const int r2 = min(base + n0l + 2, n_nodes - 1), r3 = min(base + n0l + 3, n_nodes - 1);
        float acc[4][4];
#pragma unroll
        for (int i = 0; i < 4; ++i)
#pragma unroll
            for (int j = 0; j < 4; ++j) acc[i][j] = b4[j0 + j];
#pragma unroll 4
        for (int k = 0; k < 64; k += 4) {
            ushort4 u0 = *(const ushort4*)&in[(size_t)r0 * 64 + k];
            ushort4 u1 = *(const ushort4*)&in[(size_t)r1 * 64 + k];
            ushort4 u2 = *(const ushort4*)&in[(size_t)r2 * 64 + k];
            ushort4 u3 = *(const ushort4*)&in[(size_t)r3 * 64 + k];
            float4 a0 = BF4_TO_F4(u0);
            float4 a1 = BF4_TO_F4(u1);
            float4 a2 = BF4_TO_F4(u2);
            float4 a3 = BF4_TO_F4(u3);
            float4 w0 = *(const float4*)&sW4[(k + 0) * 64 + j0];
            float4 w1 = *(const float4*)&sW4[(k + 1) * 64 + j0];
            float4 w2 = *(const float4*)&sW4[(k + 2) * 64 + j0];
            float4 w3 = *(const float4*)&sW4[(k + 3) * 64 + j0];
            GIN_STEP(a0, 0) GIN_STEP(a1, 1) GIN_STEP(a2, 2) GIN_STEP(a3, 3)
        }
#pragma unroll
        for (int i = 0; i < 4; ++i) {
            float4 t;
            t.x = fmaxf(acc[i][0], 0.f); t.y = fmaxf(acc[i][1], 0.f);
            t.z = fmaxf(acc[i][2], 0.f); t.w = fmaxf(acc[i][3], 0.f);
            *(float4*)&sTf[(n0l + i) * 68 + j0] = t;
        }
    }
    __syncthreads();      // sT ready; sW4 now dead -> sLog may overwrite
    if (tid < 160) {      // 64 nodes x 40 outs
        const int tj = tid % 10, tn = tid / 10;
        const int j0 = tj * 4, n0l = tn * 4;
        float acc[4][4];
#pragma unroll
        for (int i = 0; i < 4; ++i)
#pragma unroll
            for (int j = 0; j < 4; ++j) acc[i][j] = bfin[j0 + j];
#pragma unroll 4
        for (int k = 0; k < 64; k += 4) {
            float4 a0 = *(const float4*)&sTf[(n0l + 0) * 68 + k];
            float4 a1 = *(const float4*)&sTf[(n0l + 1) * 68 + k];
            float4 a2 = *(const float4*)&sTf[(n0l + 2) * 68 + k];
            float4 a3 = *(const float4*)&sTf[(n0l + 3) * 68 + k];
            float4 w0 = *(const float4*)&sWf[(k + 0) * 40 + j0];
            float4 w1 = *(const float4*)&sWf[(k + 1) * 40 + j0];
            float4 w2 = *(const float4*)&sWf[(k + 2) * 40 + j0];
            float4 w3 = *(const float4*)&sWf[(k + 3) * 40 + j0];
            GIN_STEP(a0, 0) GIN_STEP(a1, 1) GIN_STEP(a2, 2) GIN_STEP(a3, 3)
        }
#pragma unroll
        for (int i = 0; i < 4; ++i)
            *(float4*)&sLog[(n0l + i) * 40 + j0] = make_float4(acc[i][0], acc[i][1], acc[i][2], acc[i][3]);
    }
    __syncthreads();
    if (tid < 64) {
        const int nl = tid;
        const int n = base + nl;
        if (n < n_nodes) {
            float m = -1e30f;
            for (int j = 0; j < 40; ++j) m = fmaxf(m, sLog[nl * 40 + j]);
            float s = 0.f;
            for (int j = 0; j < 40; ++j) s += expf(sLog[nl * 40 + j] - m);
            float lse = m + logf(s);
            for (int j = 0; j < 40; j += 4) {
                float4 o;
                o.x = sLog[nl * 40 + j + 0] - lse;
                o.y = sLog[nl * 40 + j + 1] - lse;
                o.z = sLog[nl * 40 + j + 2] - lse;
                o.w = sLog[nl * 40 + j + 3] - lse;
                *(float4*)&out[(size_t)n * 40 + j] = o;
            }
        }
    }
}

// ============================ launch ============================

extern "C" void kernel_launch(void* const* d_in, const int* in_sizes, int n_in,
                              void* d_out, int out_size, void* d_ws, size_t ws_size,
                              hipStream_t stream) {
    const float* x  = (const float*)d_in[0];
    const int*   ei = (const int*)d_in[1];
    const float* W1 = (const float*)d_in[2];
    const float* b1 = (const float*)d_in[3];
    const float* W2 = (const float*)d_in[4];
    const float* b2 = (const float*)d_in[5];
    const float* W3 = (const float*)d_in[6];
    const float* b3 = (const float*)d_in[7];
    const float* W4 = (const float*)d_in[8];
    const float* b4 = (const float*)d_in[9];
    const float* Wf = (const float*)d_in[10];
    const float* bf = (const float*)d_in[11];
    float* outp = (float*)d_out;

    const int N = N_NODES_C, E = N_EDGES_C;
    const int* srcp = ei;
    const int* dstp = ei + E;

    // workspace layout (~52.9 MB)
    char* ws = (char*)d_ws;
    int*          offs  = (int*)(ws);                     // N+1 ints        -> 400128
    int*          boffs = (int*)(ws + 400128);            // NB+1 ints       -> 403328
    int*          bsums = (int*)(ws + 403328);            // 512 ints        -> 405376
    int*          cnt   = (int*)(ws + 405376);            // NB*NBLK ints    -> 1628672 (1,223,048 B used)
    unsigned int* stage = (unsigned int*)(ws + 1628672);  // E u32           -> 14428672
    int*          srcs  = (int*)(ws + 14428672);          // E ints          -> 27228672
    u16*          Ybf   = (u16*)(ws + 27228672);          // N*64 bf16       -> 40028672
    u16*          F2bf  = (u16*)(ws + 40028672);          // N*64 bf16       -> 52828672

    // ---- atomic-free bucketed CSR build ----
    passA_hist_kernel<<<NBLK, 256, 0, stream>>>(dstp, cnt, E);
    const int n_scan = NB * NBLK;                   // 305,762
    const int nblk_scan = (n_scan + 1023) / 1024;   // 299
    scan_chunks_kernel<<<nblk_scan, 256, 0, stream>>>(cnt, n_scan, bsums);
    scan_sums_kernel<<<1, 512, 0, stream>>>(bsums, nblk_scan);
    scan_add_kernel<<<nblk_scan, 256, 0, stream>>>(cnt, n_scan, bsums);
    boffs_kernel<<<1, 1024, 0, stream>>>(cnt, boffs, offs);
    passB_sort_kernel<<<NBLK, 256, 0, stream>>>(srcp, dstp, cnt, stage, E);
    bucket_finalize_kernel<<<NB, 256, 0, stream>>>(stage, boffs, offs, srcs);

    const int mlp_grid = (N + 63) / 64;
    const int gat_grid = (N + 3) / 4;

    // ---- conv1: y = bf16(x@W1); h1 = bf16(relu(y_n + sum y_src + b1)); u = bf16(relu(h1@W2+b2)@W3) ----
    dense128_kernel<<<mlp_grid, 256, 0, stream>>>(x, W1, Ybf, N);
    gather64v_kernel<<<gat_grid, 256, 0, stream>>>(Ybf, offs, srcs, b1, F2bf, N);
    fused_w2w3_kernel<<<mlp_grid, 256, 0, stream>>>(F2bf, W2, b2, W3, Ybf, N);

    // ---- conv2: h3 = bf16(relu(u_n + sum u_src + b3)); out = logsoftmax(relu(h3@W4+b4)@Wf + bf) ----
    gather64v_kernel<<<gat_grid, 256, 0, stream>>>(Ybf, offs, srcs, b3, F2bf, N);
    fused_w4final_kernel<<<mlp_grid, 256, 0, stream>>>(F2bf, W4, b4, Wf, bf, outp, N);
}

// Round 13
// 263.666 us; speedup vs baseline: 1.4083x; 1.0965x over previous
//
#include <hip/hip_runtime.h>
#include <math.h>

#define N_NODES_C 100000
#define N_EDGES_C 3200000
#define NB 782        // ceil(100000 / 128) buckets of 128 nodes
#define BNODES 128
#define LDS_CAP 6144  // per-bucket LDS staging capacity (mean ~4092, +32 sigma)
#define CHUNK 8192    // edges per partition block
#define NBLK 391      // ceil(N_EDGES_C / CHUNK)

typedef unsigned short u16;
typedef __attribute__((ext_vector_type(8))) short short8v;   // 8 bf16 = 4 VGPR
typedef __attribute__((ext_vector_type(4))) float float4v;   // mfma accumulator

__device__ __forceinline__ float bf2f(u16 u) {
    unsigned int t = ((unsigned int)u) << 16;
    return __uint_as_float(t);
}
__device__ __forceinline__ u16 f2bf(float f) {  // round-to-nearest-even
    unsigned int x = __float_as_uint(f);
    x += 0x7fffu + ((x >> 16) & 1u);
    return (u16)(x >> 16);
}

// ============================ atomic-free bucketed partition ============================

__global__ __launch_bounds__(256) void passA_hist_kernel(const int* __restrict__ dst,
                                                         int* __restrict__ cnt, int n_edges) {
    __shared__ int h[NB];
    for (int i = threadIdx.x; i < NB; i += 256) h[i] = 0;
    __syncthreads();
    const int blk = blockIdx.x;
    const int e0 = blk * CHUNK;
    const int cntE = min(CHUNK, n_edges - e0);
    for (int i = threadIdx.x * 4; i < cntE; i += 1024) {
        int4 d4 = *(const int4*)&dst[e0 + i];
        atomicAdd(&h[d4.x >> 7], 1); atomicAdd(&h[d4.y >> 7], 1);
        atomicAdd(&h[d4.z >> 7], 1); atomicAdd(&h[d4.w >> 7], 1);
    }
    __syncthreads();
    for (int i = threadIdx.x; i < NB; i += 256) cnt[i * NBLK + blk] = h[i];
}

__global__ __launch_bounds__(256) void scan_chunks_kernel(int* __restrict__ a, int n, int* __restrict__ bsums) {
    __shared__ int s[256];
    const int tid = threadIdx.x;
    int base = blockIdx.x * 1024 + tid * 4;
    int v[4];
#pragma unroll
    for (int i = 0; i < 4; ++i) v[i] = (base + i < n) ? a[base + i] : 0;
    int tsum = v[0] + v[1] + v[2] + v[3];
    s[tid] = tsum;
    __syncthreads();
    for (int off = 1; off < 256; off <<= 1) {
        int t = (tid >= off) ? s[tid - off] : 0;
        __syncthreads();
        s[tid] += t;
        __syncthreads();
    }
    int run = s[tid] - tsum;
#pragma unroll
    for (int i = 0; i < 4; ++i) {
        run += v[i];
        if (base + i < n) a[base + i] = run;
    }
    if (tid == 255) bsums[blockIdx.x] = s[255];
}

// exclusive scan of bsums[0..nb), nb <= 512, single block of 512
__global__ __launch_bounds__(512) void scan_sums_kernel(int* __restrict__ bsums, int nb) {
    __shared__ int s[512];
    const int tid = threadIdx.x;
    int v = (tid < nb) ? bsums[tid] : 0;
    s[tid] = v;
    __syncthreads();
    for (int off = 1; off < 512; off <<= 1) {
        int t = (tid >= off) ? s[tid - off] : 0;
        __syncthreads();
        s[tid] += t;
        __syncthreads();
    }
    if (tid < nb) bsums[tid] = s[tid] - v;
}

__global__ __launch_bounds__(256) void scan_add_kernel(int* __restrict__ a, int n, const int* __restrict__ bsums) {
    int base = blockIdx.x * 1024 + threadIdx.x * 4;
    int add = bsums[blockIdx.x];
#pragma unroll
    for (int i = 0; i < 4; ++i)
        if (base + i < n) a[base + i] += add;
}

__global__ __launch_bounds__(1024) void boffs_kernel(const int* __restrict__ incl,
                                                     int* __restrict__ boffs,
                                                     int* __restrict__ offs) {
    const int b = threadIdx.x;
    if (b < NB) boffs[b] = b ? incl[b * NBLK - 1] : 0;
    if (b == 0) {
        int total = incl[NB * NBLK - 1];
        boffs[NB] = total;
        offs[N_NODES_C] = total;
    }
}

// pass B (LDS sort, no dst staging): counting sort by bucket, then burst-write each run
__global__ __launch_bounds__(256) void passB_sort_kernel(const int* __restrict__ src,
                                                         const int* __restrict__ dst,
                                                         const int* __restrict__ incl,
                                                         unsigned int* __restrict__ stage,
                                                         int n_edges) {
    __shared__ unsigned int spack[CHUNK];   // 32 KB
    __shared__ int hist[NB];
    __shared__ int lcur[NB];
    __shared__ int tsum[256];
    const int blk = blockIdx.x, tid = threadIdx.x;
    const int e0 = blk * CHUNK;
    const int cntE = min(CHUNK, n_edges - e0);

    for (int b = tid; b < NB; b += 256) hist[b] = 0;
    __syncthreads();

    for (int i = tid * 4; i < cntE; i += 1024) {
        int4 d4 = *(const int4*)&dst[e0 + i];
        atomicAdd(&hist[d4.x >> 7], 1); atomicAdd(&hist[d4.y >> 7], 1);
        atomicAdd(&hist[d4.z >> 7], 1); atomicAdd(&hist[d4.w >> 7], 1);
    }
    __syncthreads();

    {
        int loc[4];
        const int bi = tid * 4;
        int s = 0;
#pragma unroll
        for (int k = 0; k < 4; ++k) {
            int idx = bi + k;
            loc[k] = (idx < NB) ? hist[idx] : 0;
            s += loc[k];
        }
        tsum[tid] = s;
        __syncthreads();
        for (int off = 1; off < 256; off <<= 1) {
            int t = (tid >= off) ? tsum[tid - off] : 0;
            __syncthreads();
            tsum[tid] += t;
            __syncthreads();
        }
        int run = tsum[tid] - s;
#pragma unroll
        for (int k = 0; k < 4; ++k) {
            int idx = bi + k;
            if (idx < NB) {
                int h = loc[k];
                hist[idx] = run;
                lcur[idx] = run;
                run += h;
            }
        }
    }
    __syncthreads();

    for (int i = tid * 4; i < cntE; i += 1024) {
        int4 d4 = *(const int4*)&dst[e0 + i];
        int4 s4 = *(const int4*)&src[e0 + i];
        int p;
        p = atomicAdd(&lcur[d4.x >> 7], 1); spack[p] = (unsigned)s4.x | (((unsigned)d4.x & 127u) << 17);
        p = atomicAdd(&lcur[d4.y >> 7], 1); spack[p] = (unsigned)s4.y | (((unsigned)d4.y & 127u) << 17);
        p = atomicAdd(&lcur[d4.z >> 7], 1); spack[p] = (unsigned)s4.z | (((unsigned)d4.z & 127u) << 17);
        p = atomicAdd(&lcur[d4.w >> 7], 1); spack[p] = (unsigned)s4.w | (((unsigned)d4.w & 127u) << 17);
    }
    __syncthreads();

    for (int b = tid; b < NB; b += 256) {
        int l0 = hist[b];
        int l1 = (b + 1 < NB) ? hist[b + 1] : cntE;
        int idx = b * NBLK + blk;
        int g0 = idx ? incl[idx - 1] : 0;
        for (int j = l0; j < l1; ++j) stage[g0 + (j - l0)] = spack[j];
    }
}

__global__ __launch_bounds__(256) void bucket_finalize_kernel(const unsigned int* __restrict__ stage,
                                                              const int* __restrict__ boffs,
                                                              int* __restrict__ offs,
                                                              int* __restrict__ srcs) {
    __shared__ int hist[BNODES];
    __shared__ int excl[BNODES];
    __shared__ int curs[BNODES];
    __shared__ int sbuf[LDS_CAP];
    const int b = blockIdx.x, tid = threadIdx.x;
    const int base = boffs[b];
    const int count = boffs[b + 1] - base;
    const int n0 = b * BNODES;
    for (int i = tid; i < BNODES; i += 256) hist[i] = 0;
    __syncthreads();
    for (int i = tid; i < count; i += 256) {
        unsigned int w = stage[base + i];
        atomicAdd(&hist[w >> 17], 1);
    }
    __syncthreads();
    if (tid < BNODES) excl[tid] = hist[tid];
    __syncthreads();
    for (int off = 1; off < BNODES; off <<= 1) {
        int t = 0;
        if (tid < BNODES && tid >= off) t = excl[tid - off];
        __syncthreads();
        if (tid < BNODES) excl[tid] += t;
        __syncthreads();
    }
    if (tid < BNODES) {
        int ex = excl[tid] - hist[tid];
        int n = n0 + tid;
        if (n < N_NODES_C) offs[n] = base + ex;
        curs[tid] = ex;
    }
    __syncthreads();
    if (count <= LDS_CAP) {
        for (int i = tid; i < count; i += 256) {
            unsigned int w = stage[base + i];
            int p = atomicAdd(&curs[w >> 17], 1);
            sbuf[p] = (int)(w & 0x1FFFFu);
        }
        __syncthreads();
        for (int i = tid; i < count; i += 256) srcs[base + i] = sbuf[i];
    } else {
        for (int i = tid; i < count; i += 256) {
            unsigned int w = stage[base + i];
            int p = atomicAdd(&curs[w >> 17], 1);
            srcs[base + p] = (int)(w & 0x1FFFFu);
        }
    }
}

// ====== gather64v: bf16 in, bf16 out; 16 lanes/row, 4 row-slots/wave, 32-row unroll ======

__global__ __launch_bounds__(256) void gather64v_kernel(const u16* __restrict__ feat,
                                                        const int* __restrict__ offs,
                                                        const int* __restrict__ srcs,
                                                        const float* __restrict__ bias,
                                                        u16* __restrict__ out, int n_nodes) {
    const int wave = threadIdx.x >> 6;
    const int lane = threadIdx.x & 63;
    const int grp  = lane >> 4;
    const int cl   = lane & 15;
    const int n = blockIdx.x * 4 + wave;
    if (n >= n_nodes) return;

    float a0 = 0.f, a1 = 0.f, a2 = 0.f, a3 = 0.f;
    if (grp == 0) {
        ushort4 v = *(const ushort4*)&feat[(size_t)n * 64 + cl * 4];
        a0 = bf2f(v.x); a1 = bf2f(v.y); a2 = bf2f(v.z); a3 = bf2f(v.w);
    }
    const int s0 = offs[n], s1 = offs[n + 1];
    int i = s0;
    for (; i + 32 <= s1; i += 32) {
        int r[8];
#pragma unroll
        for (int u = 0; u < 8; ++u) r[u] = srcs[i + u * 4 + grp];
        ushort4 v[8];
#pragma unroll
        for (int u = 0; u < 8; ++u) v[u] = *(const ushort4*)&feat[(size_t)r[u] * 64 + cl * 4];
#pragma unroll
        for (int u = 0; u < 8; ++u) {
            a0 += bf2f(v[u].x); a1 += bf2f(v[u].y); a2 += bf2f(v[u].z); a3 += bf2f(v[u].w);
        }
    }
    for (; i + 8 <= s1; i += 8) {
        int ra = srcs[i + grp];
        int rb = srcs[i + 4 + grp];
        ushort4 va = *(const ushort4*)&feat[(size_t)ra * 64 + cl * 4];
        ushort4 vb = *(const ushort4*)&feat[(size_t)rb * 64 + cl * 4];
        a0 += bf2f(va.x); a1 += bf2f(va.y); a2 += bf2f(va.z); a3 += bf2f(va.w);
        a0 += bf2f(vb.x); a1 += bf2f(vb.y); a2 += bf2f(vb.z); a3 += bf2f(vb.w);
    }
    for (; i + 4 <= s1; i += 4) {
        int rr = srcs[i + grp];
        ushort4 v = *(const ushort4*)&feat[(size_t)rr * 64 + cl * 4];
        a0 += bf2f(v.x); a1 += bf2f(v.y); a2 += bf2f(v.z); a3 += bf2f(v.w);
    }
    if (i + grp < s1) {
        int rr = srcs[i + grp];
        ushort4 v = *(const ushort4*)&feat[(size_t)rr * 64 + cl * 4];
        a0 += bf2f(v.x); a1 += bf2f(v.y); a2 += bf2f(v.z); a3 += bf2f(v.w);
    }
    a0 += __shfl_xor(a0, 16); a1 += __shfl_xor(a1, 16);
    a2 += __shfl_xor(a2, 16); a3 += __shfl_xor(a3, 16);
    a0 += __shfl_xor(a0, 32); a1 += __shfl_xor(a1, 32);
    a2 += __shfl_xor(a2, 32); a3 += __shfl_xor(a3, 32);
    if (lane < 16) {
        float4 b = *(const float4*)&bias[cl * 4];
        ushort4 o;
        o.x = f2bf(fmaxf(a0 + b.x, 0.f));
        o.y = f2bf(fmaxf(a1 + b.y, 0.f));
        o.z = f2bf(fmaxf(a2 + b.z, 0.f));
        o.w = f2bf(fmaxf(a3 + b.w, 0.f));
        *(ushort4*)&out[(size_t)n * 64 + cl * 4] = o;
    }
}

// GEMM quad-step macro (VALU path, dense128 only)
#define GIN_STEP(ai, i)                                                                               \
    acc[i][0] += ai.x * w0.x; acc[i][1] += ai.x * w0.y; acc[i][2] += ai.x * w0.z; acc[i][3] += ai.x * w0.w; \
    acc[i][0] += ai.y * w1.x; acc[i][1] += ai.y * w1.y; acc[i][2] += ai.y * w1.z; acc[i][3] += ai.y * w1.w; \
    acc[i][0] += ai.z * w2.x; acc[i][1] += ai.z * w2.y; acc[i][2] += ai.z * w2.z; acc[i][3] += ai.z * w2.w; \
    acc[i][0] += ai.w * w3.x; acc[i][1] += ai.w * w3.y; acc[i][2] += ai.w * w3.z; acc[i][3] += ai.w * w3.w;

// ====== dense128: out_bf16 = x @ W1  (W1 in LDS; inputs direct from global; unroll 4) ======

__global__ __launch_bounds__(256) void dense128_kernel(const float* __restrict__ in,
                                                       const float* __restrict__ W,
                                                       u16* __restrict__ out, int n_nodes) {
    __shared__ float sW[128 * 64];   // 32 KB
    const int tid = threadIdx.x;
    for (int i = tid; i < 128 * 16; i += 256) ((float4*)sW)[i] = ((const float4*)W)[i];
    __syncthreads();
    const int tj = tid & 15, tn = tid >> 4;
    const int j0 = tj * 4, n0 = blockIdx.x * 64 + tn * 4;
    const int r0 = min(n0 + 0, n_nodes - 1), r1 = min(n0 + 1, n_nodes - 1);
    const int r2 = min(n0 + 2, n_nodes - 1), r3 = min(n0 + 3, n_nodes - 1);
    float acc[4][4];
#pragma unroll
    for (int i = 0; i < 4; ++i)
#pragma unroll
        for (int j = 0; j < 4; ++j) acc[i][j] = 0.f;
#pragma unroll 4
    for (int k = 0; k < 128; k += 4) {
        float4 a0 = *(const float4*)&in[(size_t)r0 * 128 + k];
        float4 a1 = *(const float4*)&in[(size_t)r1 * 128 + k];
        float4 a2 = *(const float4*)&in[(size_t)r2 * 128 + k];
        float4 a3 = *(const float4*)&in[(size_t)r3 * 128 + k];
        float4 w0 = *(const float4*)&sW[(k + 0) * 64 + j0];
        float4 w1 = *(const float4*)&sW[(k + 1) * 64 + j0];
        float4 w2 = *(const float4*)&sW[(k + 2) * 64 + j0];
        float4 w3 = *(const float4*)&sW[(k + 3) * 64 + j0];
        GIN_STEP(a0, 0) GIN_STEP(a1, 1) GIN_STEP(a2, 2) GIN_STEP(a3, 3)
    }
#pragma unroll
    for (int i = 0; i < 4; ++i) {
        int n = n0 + i;
        if (n < n_nodes) {
            ushort4 o;
            o.x = f2bf(acc[i][0]); o.y = f2bf(acc[i][1]);
            o.z = f2bf(acc[i][2]); o.w = f2bf(acc[i][3]);
            *(ushort4*)&out[(size_t)n * 64 + j0] = o;
        }
    }
}

// ====== MFMA fused: T = relu(in@W2+b2); out_bf16 = T@W3 ======
// B-fragments pre-swizzled in LDS: frag (kt,jt), lane l, elem i <- W[kt*32+(l>>4)*8+i][jt*16+(l&15)]
// A-fragment: lane l, elem i <- A[l&15][kt*32+(l>>4)*8+i]  (contiguous 16B load)
// D: row=(l>>4)*4+r, col=l&15   [m89-verified]

__global__ __launch_bounds__(256) void mfma_w2w3_kernel(const u16* __restrict__ in,
                                                        const float* __restrict__ W2,
                                                        const float* __restrict__ b2,
                                                        const float* __restrict__ W3,
                                                        u16* __restrict__ out, int n_nodes) {
    __shared__ u16 w2f[4096];     // 8 frags x 512
    __shared__ u16 w3f[4096];
    __shared__ u16 sT[64 * 72];   // padded stride 72 u16 = 144 B (16B-aligned, 2-way banks)
    const int tid = threadIdx.x;
    for (int idx = tid; idx < 4096; idx += 256) {
        int frag = idx >> 9;          // kt*4+jt
        int within = idx & 511;
        int lane = within >> 3;
        int i = within & 7;
        int kt = frag >> 2, jt = frag & 3;
        int k = kt * 32 + (lane >> 4) * 8 + i;
        int j = jt * 16 + (lane & 15);
        w2f[idx] = f2bf(W2[k * 64 + j]);
        w3f[idx] = f2bf(W3[k * 64 + j]);
    }
    __syncthreads();
    const int w = tid >> 6, l = tid & 63;
    const int nbase = blockIdx.x * 64 + w * 16;
    const int arow = min(nbase + (l & 15), n_nodes - 1);
    // GEMM1: A from global bf16 (2 ktiles)
    short8v a0 = *(const short8v*)&in[(size_t)arow * 64 + (l >> 4) * 8];
    short8v a1 = *(const short8v*)&in[(size_t)arow * 64 + 32 + (l >> 4) * 8];
#pragma unroll
    for (int jt = 0; jt < 4; ++jt) {
        float bv = b2[jt * 16 + (l & 15)];
        float4v acc = {bv, bv, bv, bv};
        acc = __builtin_amdgcn_mfma_f32_16x16x32_bf16(a0, *(short8v*)&w2f[(0 * 4 + jt) * 512 + l * 8], acc, 0, 0, 0);
        acc = __builtin_amdgcn_mfma_f32_16x16x32_bf16(a1, *(short8v*)&w2f[(1 * 4 + jt) * 512 + l * 8], acc, 0, 0, 0);
#pragma unroll
        for (int r = 0; r < 4; ++r) {
            int row = w * 16 + (l >> 4) * 4 + r;
            sT[row * 72 + jt * 16 + (l & 15)] = f2bf(fmaxf(acc[r], 0.f));
        }
    }
    __syncthreads();
    // GEMM2: A from sT
    const int trow = w * 16 + (l & 15);
    short8v t0 = *(short8v*)&sT[trow * 72 + (l >> 4) * 8];
    short8v t1 = *(short8v*)&sT[trow * 72 + 32 + (l >> 4) * 8];
#pragma unroll
    for (int jt = 0; jt < 4; ++jt) {
        float4v acc = {0.f, 0.f, 0.f, 0.f};
        acc = __builtin_amdgcn_mfma_f32_16x16x32_bf16(t0, *(short8v*)&w3f[(0 * 4 + jt) * 512 + l * 8], acc, 0, 0, 0);
        acc = __builtin_amdgcn_mfma_f32_16x16x32_bf16(t1, *(short8v*)&w3f[(1 * 4 + jt) * 512 + l * 8], acc, 0, 0, 0);
#pragma unroll
        for (int r = 0; r < 4; ++r) {
            int n = nbase + (l >> 4) * 4 + r;
            if (n < n_nodes) out[(size_t)n * 64 + jt * 16 + (l & 15)] = f2bf(acc[r]);
        }
    }
}

// ====== MFMA fused final: T = relu(in@W4+b4); logits = T@Wf+bf; out = log_softmax ======

__global__ __launch_bounds__(256) void mfma_w4final_kernel(const u16* __restrict__ in,
                                                           const float* __restrict__ W4,
                                                           const float* __restrict__ b4,
                                                           const float* __restrict__ Wf,
                                                           const float* __restrict__ bfin,
                                                           float* __restrict__ out, int n_nodes) {
    __shared__ u16 w4f[4096];       // 8 frags
    __shared__ u16 wff[3072];       // 6 frags (N padded 40->48)
    __shared__ u16 sT[64 * 72];
    __shared__ float sLog[64 * 40];
    const int tid = threadIdx.x;
    for (int idx = tid; idx < 4096; idx += 256) {
        int frag = idx >> 9;
        int within = idx & 511;
        int lane = within >> 3;
        int i = within & 7;
        int kt = frag >> 2, jt = frag & 3;
        int k = kt * 32 + (lane >> 4) * 8 + i;
        int j = jt * 16 + (lane & 15);
        w4f[idx] = f2bf(W4[k * 64 + j]);
    }
    for (int idx = tid; idx < 3072; idx += 256) {
        int frag = idx >> 9;          // kt*3+jt
        int within = idx & 511;
        int lane = within >> 3;
        int i = within & 7;
        int kt = frag / 3, jt = frag % 3;
        int k = kt * 32 + (lane >> 4) * 8 + i;
        int j = jt * 16 + (lane & 15);
        wff[idx] = (j < 40) ? f2bf(Wf[k * 40 + j]) : (u16)0;
    }
    __syncthreads();
    const int w = tid >> 6, l = tid & 63;
    const int nbase = blockIdx.x * 64 + w * 16;
    const int arow = min(nbase + (l & 15), n_nodes - 1);
    // GEMM1
    short8v a0 = *(const short8v*)&in[(size_t)arow * 64 + (l >> 4) * 8];
    short8v a1 = *(const short8v*)&in[(size_t)arow * 64 + 32 + (l >> 4) * 8];
#pragma unroll
    for (int jt = 0; jt < 4; ++jt) {
        float bv = b4[jt * 16 + (l & 15)];
        float4v acc = {bv, bv, bv, bv};
        acc = __builtin_amdgcn_mfma_f32_16x16x32_bf16(a0, *(short8v*)&w4f[(0 * 4 + jt) * 512 + l * 8], acc, 0, 0, 0);
        acc = __builtin_amdgcn_mfma_f32_16x16x32_bf16(a1, *(short8v*)&w4f[(1 * 4 + jt) * 512 + l * 8], acc, 0, 0, 0);
#pragma unroll
        for (int r = 0; r < 4; ++r) {
            int row = w * 16 + (l >> 4) * 4 + r;
            sT[row * 72 + jt * 16 + (l & 15)] = f2bf(fmaxf(acc[r], 0.f));
        }
    }
    __syncthreads();
    // GEMM2: logits (N=40, padded to 48)
    const int trow = w * 16 + (l & 15);
    short8v t0 = *(short8v*)&sT[trow * 72 + (l >> 4) * 8];
    short8v t1 = *(short8v*)&sT[trow * 72 + 32 + (l >> 4) * 8];
#pragma unroll
    for (int jt = 0; jt < 3; ++jt) {
        int col = jt * 16 + (l & 15);
        float bv = (col < 40) ? bfin[col] : 0.f;
        float4v acc = {bv, bv, bv, bv};
        acc = __builtin_amdgcn_mfma_f32_16x16x32_bf16(t0, *(short8v*)&wff[(0 * 3 + jt) * 512 + l * 8], acc, 0, 0, 0);
        acc = __builtin_amdgcn_mfma_f32_16x16x32_bf16(t1, *(short8v*)&wff[(1 * 3 + jt) * 512 + l * 8], acc, 0, 0, 0);
#pragma unroll
        for (int r = 0; r < 4; ++r) {
            int row = w * 16 + (l >> 4) * 4 + r;
            if (col < 40) sLog[row * 40 + col] = acc[r];
        }
    }
    __syncthreads();
    if (tid < 64) {
        const int nl = tid;
        const int n = blockIdx.x * 64 + nl;
        if (n < n_nodes) {
            float m = -1e30f;
            for (int j = 0; j < 40; ++j) m = fmaxf(m, sLog[nl * 40 + j]);
            float s = 0.f;
            for (int j = 0; j < 40; ++j) s += expf(sLog[nl * 40 + j] - m);
            float lse = m + logf(s);
            for (int j = 0; j < 40; j += 4) {
                float4 o;
                o.x = sLog[nl * 40 + j + 0] - lse;
                o.y = sLog[nl * 40 + j + 1] - lse;
                o.z = sLog[nl * 40 + j + 2] - lse;
                o.w = sLog[nl * 40 + j + 3] - lse;
                *(float4*)&out[(size_t)n * 40 + j] = o;
            }
        }
    }
}

// ============================ launch ============================

extern "C" void kernel_launch(void* const* d_in, const int* in_sizes, int n_in,
                              void* d_out, int out_size, void* d_ws, size_t ws_size,
                              hipStream_t stream) {
    const float* x  = (const float*)d_in[0];
    const int*   ei = (const int*)d_in[1];
    const float* W1 = (const float*)d_in[2];
    const float* b1 = (const float*)d_in[3];
    const float* W2 = (const float*)d_in[4];
    const float* b2 = (const float*)d_in[5];
    const float* W3 = (const float*)d_in[6];
    const float* b3 = (const float*)d_in[7];
    const float* W4 = (const float*)d_in[8];
    const float* b4 = (const float*)d_in[9];
    const float* Wf = (const float*)d_in[10];
    const float* bf = (const float*)d_in[11];
    float* outp = (float*)d_out;

    const int N = N_NODES_C, E = N_EDGES_C;
    const int* srcp = ei;
    const int* dstp = ei + E;

    // workspace layout (~52.9 MB)
    char* ws = (char*)d_ws;
    int*          offs  = (int*)(ws);                     // N+1 ints        -> 400128
    int*          boffs = (int*)(ws + 400128);            // NB+1 ints       -> 403328
    int*          bsums = (int*)(ws + 403328);            // 512 ints        -> 405376
    int*          cnt   = (int*)(ws + 405376);            // NB*NBLK ints    -> 1628672
    unsigned int* stage = (unsigned int*)(ws + 1628672);  // E u32           -> 14428672
    int*          srcs  = (int*)(ws + 14428672);          // E ints          -> 27228672
    u16*          Ybf   = (u16*)(ws + 27228672);          // N*64 bf16       -> 40028672
    u16*          F2bf  = (u16*)(ws + 40028672);          // N*64 bf16       -> 52828672

    // ---- atomic-free bucketed CSR build ----
    passA_hist_kernel<<<NBLK, 256, 0, stream>>>(dstp, cnt, E);
    const int n_scan = NB * NBLK;
    const int nblk_scan = (n_scan + 1023) / 1024;
    scan_chunks_kernel<<<nblk_scan, 256, 0, stream>>>(cnt, n_scan, bsums);
    scan_sums_kernel<<<1, 512, 0, stream>>>(bsums, nblk_scan);
    scan_add_kernel<<<nblk_scan, 256, 0, stream>>>(cnt, n_scan, bsums);
    boffs_kernel<<<1, 1024, 0, stream>>>(cnt, boffs, offs);
    passB_sort_kernel<<<NBLK, 256, 0, stream>>>(srcp, dstp, cnt, stage, E);
    bucket_finalize_kernel<<<NB, 256, 0, stream>>>(stage, boffs, offs, srcs);

    const int mlp_grid = (N + 63) / 64;
    const int gat_grid = (N + 3) / 4;

    // ---- conv1: y = bf16(x@W1); h1 = bf16(relu(y_n + sum y_src + b1)); u = bf16(relu(h1@W2+b2)@W3) ----
    dense128_kernel<<<mlp_grid, 256, 0, stream>>>(x, W1, Ybf, N);
    gather64v_kernel<<<gat_grid, 256, 0, stream>>>(Ybf, offs, srcs, b1, F2bf, N);
    mfma_w2w3_kernel<<<mlp_grid, 256, 0, stream>>>(F2bf, W2, b2, W3, Ybf, N);

    // ---- conv2: h3 = bf16(relu(u_n + sum u_src + b3)); out = logsoftmax(relu(h3@W4+b4)@Wf + bf) ----
    gather64v_kernel<<<gat_grid, 256, 0, stream>>>(Ybf, offs, srcs, b3, F2bf, N);
    mfma_w4final_kernel<<<mlp_grid, 256, 0, stream>>>(F2bf, W4, b4, Wf, bf, outp, N);
}